// Round 2
// baseline (750.636 us; speedup 1.0000x reference)
//
#include <hip/hip_runtime.h>
#include <math.h>

#define BATCH 2048
#define SEQL 65
#define EMB 512
#define NHEADS 8
#define HD 64
#define NPATCH 64
#define PFEAT 48
#define HIDDIM 1024
#define NCLS 10

// ---- K0a: Wc[h*64+k][f] = sum_d wq[h,k,d] * proj_w[d,f]  (512x48) ----
__global__ __launch_bounds__(256) void k_wc(
    const float* __restrict__ wq, const float* __restrict__ proj_w,
    float* __restrict__ Wc)
{
  int idx = blockIdx.x*256 + threadIdx.x;          // 512*48 = 24576 entries
  int hk = idx / PFEAT, f = idx - hk*PFEAT;
  const float* wr = wq + (size_t)hk*EMB;
  float acc = 0.f;
  for (int d = 0; d < EMB; ++d) acc += wr[d]*proj_w[d*PFEAT + f];
  Wc[idx] = acc;
}

// ---- K0b: qbias[h][s][k] = sum_d (pos[s,d] + (s? proj_b : cls)[d]) * wq[h,k,d] + bq[h,k] ----
__global__ __launch_bounds__(256) void k_qbias(
    const float* __restrict__ wq, const float* __restrict__ bq,
    const float* __restrict__ cls, const float* __restrict__ pos,
    const float* __restrict__ proj_b, float* __restrict__ qbias)
{
  int idx = blockIdx.x*256 + threadIdx.x;          // 8*65*64 = 33280 entries
  int h = idx / (SEQL*HD); int rem = idx - h*SEQL*HD;
  int s = rem / HD, k = rem - s*HD;
  const float* wr = wq + ((size_t)h*HD + k)*EMB;
  const float* po = pos + (size_t)s*EMB;
  float acc = bq[h*HD + k];
  if (s == 0) { for (int d = 0; d < EMB; ++d) acc += (po[d] + cls[d])   *wr[d]; }
  else        { for (int d = 0; d < EMB; ++d) acc += (po[d] + proj_b[d])*wr[d]; }
  qbias[idx] = acc;
}

// ---- K1: per (b,h): q from patches, S=qq^T/8, column softmax, att row 0 -> mh0 ----
__global__ __launch_bounds__(256) void k_attn(
    const float* __restrict__ x, const float* __restrict__ Wc,
    const float* __restrict__ qbias, float* __restrict__ mh0)
{
  __shared__ float buf[SEQL*66];    // stage1: P[64][49]; stage2: S[65][66]
  __shared__ float Wcs[HD*49];
  __shared__ float Qs[SEQL*65];
  __shared__ float p0v[SEQL];
  const int bh = blockIdx.x, b = bh >> 3, h = bh & 7;
  const int tid = threadIdx.x, tx = tid & 15, ty = tid >> 4;
  const float* xb = x + (size_t)b*3*32*32;

  // patchify image b into buf (stride 49)
  for (int i = tid; i < NPATCH*PFEAT; i += 256) {
    int p = i / PFEAT, f = i - p*PFEAT;
    int ni = p >> 3, nj = p & 7;
    int c = f >> 4, r = f & 15, pi = r >> 2, pj = r & 3;
    buf[p*49+f] = xb[c*1024 + (ni*4+pi)*32 + (nj*4+pj)];
  }
  // load combined weights for this head (stride 49)
  const float* wch = Wc + (size_t)h*HD*PFEAT;
  for (int i = tid; i < HD*PFEAT; i += 256) {
    int k = i / PFEAT, f = i - k*PFEAT;
    Wcs[k*49+f] = wch[i];
  }
  __syncthreads();

  // stage 1: q[1+r][k] = P[r]·Wc[k] + qbias ; q[0][k] = qbias[0][k]
  const float* qb = qbias + (size_t)h*SEQL*HD;
  {
    float acc[4][4];
    #pragma unroll
    for (int i = 0; i < 4; ++i)
      #pragma unroll
      for (int j = 0; j < 4; ++j) acc[i][j] = 0.f;
    for (int f = 0; f < PFEAT; ++f) {
      float av[4], bv[4];
      #pragma unroll
      for (int i = 0; i < 4; ++i) av[i] = buf[(ty*4+i)*49+f];
      #pragma unroll
      for (int j = 0; j < 4; ++j) bv[j] = Wcs[(tx*4+j)*49+f];
      #pragma unroll
      for (int i = 0; i < 4; ++i)
        #pragma unroll
        for (int j = 0; j < 4; ++j) acc[i][j] += av[i]*bv[j];
    }
    #pragma unroll
    for (int i = 0; i < 4; ++i) {
      int s = 1 + ty*4 + i;
      #pragma unroll
      for (int j = 0; j < 4; ++j) {
        int k = tx*4 + j;
        Qs[s*65 + k] = acc[i][j] + qb[s*HD + k];
      }
    }
    if (tid < HD) Qs[tid] = qb[tid];   // cls row
  }
  __syncthreads();

  // stage 2: S[s][t] = (q_s · q_t)/8  -> buf stride 66
  {
    float acc2[5][5];
    #pragma unroll
    for (int i = 0; i < 5; ++i)
      #pragma unroll
      for (int j = 0; j < 5; ++j) acc2[i][j] = 0.f;
    for (int f = 0; f < HD; ++f) {
      float av[5], bv[5];
      #pragma unroll
      for (int i = 0; i < 5; ++i) { int s = ty + 16*i; av[i] = (s < SEQL) ? Qs[s*65+f] : 0.f; }
      #pragma unroll
      for (int j = 0; j < 5; ++j) { int t = tx + 16*j; bv[j] = (t < SEQL) ? Qs[t*65+f] : 0.f; }
      #pragma unroll
      for (int i = 0; i < 5; ++i)
        #pragma unroll
        for (int j = 0; j < 5; ++j) acc2[i][j] += av[i]*bv[j];
    }
    __syncthreads();   // stage-1 buf reads done before overwrite
    #pragma unroll
    for (int i = 0; i < 5; ++i) {
      int s = ty + 16*i;
      if (s < SEQL) {
        #pragma unroll
        for (int j = 0; j < 5; ++j) {
          int t = tx + 16*j;
          if (t < SEQL) buf[s*66+t] = acc2[i][j]*0.125f;
        }
      }
    }
  }
  __syncthreads();

  // stage 3: softmax over s (columns); keep only row-0 probabilities
  if (tid < SEQL) {
    float m = -1e30f;
    for (int s = 0; s < SEQL; ++s) m = fmaxf(m, buf[s*66+tid]);
    float sum = 0.f;
    for (int s = 0; s < SEQL; ++s) sum += expf(buf[s*66+tid] - m);
    p0v[tid] = expf(buf[tid] - m) / sum;
  }
  __syncthreads();

  // stage 4: att0[k] = sum_t p0[t] * q[t][k]
  if (tid < HD) {
    float a = 0.f;
    for (int t = 0; t < SEQL; ++t) a += p0v[t]*Qs[t*65+tid];
    mh0[(size_t)b*EMB + h*HD + tid] = a;
  }
}

// ---- K2/K3: C[M][N] = A[M][K] @ W[N][K]^T + bias (optional exact GELU) ----
template<bool GELU>
__global__ __launch_bounds__(256) void k_ffn(
    const float* __restrict__ A, const float* __restrict__ W,
    const float* __restrict__ bias, float* __restrict__ C, int N, int K)
{
  __shared__ float As2[16*65];
  __shared__ float Bs2[16*65];
  const int tid = threadIdx.x;
  const int m0 = blockIdx.x * 64, n0 = blockIdx.y * 64;
  const int tmr = (tid >> 4) & 15, tmc = tid & 15;
  const int lr = tid >> 2, lk = (tid & 3) << 2;
  float acc[4][4];
  #pragma unroll
  for (int i = 0; i < 4; ++i)
    #pragma unroll
    for (int j = 0; j < 4; ++j) acc[i][j] = 0.f;

  for (int k0 = 0; k0 < K; k0 += 16) {
    float4 a4 = *(const float4*)(A + (size_t)(m0+lr)*K + k0 + lk);
    float4 b4 = *(const float4*)(W + (size_t)(n0+lr)*K + k0 + lk);
    As2[(lk+0)*65+lr] = a4.x; As2[(lk+1)*65+lr] = a4.y; As2[(lk+2)*65+lr] = a4.z; As2[(lk+3)*65+lr] = a4.w;
    Bs2[(lk+0)*65+lr] = b4.x; Bs2[(lk+1)*65+lr] = b4.y; Bs2[(lk+2)*65+lr] = b4.z; Bs2[(lk+3)*65+lr] = b4.w;
    __syncthreads();
    #pragma unroll
    for (int kk = 0; kk < 16; ++kk) {
      float av[4], bv[4];
      #pragma unroll
      for (int i = 0; i < 4; ++i) av[i] = As2[kk*65 + tmr*4+i];
      #pragma unroll
      for (int j = 0; j < 4; ++j) bv[j] = Bs2[kk*65 + tmc*4+j];
      #pragma unroll
      for (int i = 0; i < 4; ++i)
        #pragma unroll
        for (int j = 0; j < 4; ++j) acc[i][j] += av[i]*bv[j];
    }
    __syncthreads();
  }
  #pragma unroll
  for (int i = 0; i < 4; ++i) {
    #pragma unroll
    for (int j = 0; j < 4; ++j) {
      int m = m0 + tmr*4+i, n = n0 + tmc*4+j;
      float c = acc[i][j] + bias[n];
      if (GELU) c = 0.5f*c*(1.f + erff(c*0.70710678118654752f));
      C[(size_t)m*N + n] = c;
    }
  }
}

// ---- K4: logits = H @ w2^T + b2 ----
__global__ __launch_bounds__(256) void k_logits(
    const float* __restrict__ Hh, const float* __restrict__ w2,
    const float* __restrict__ b2, float* __restrict__ out)
{
  const int r = blockIdx.x*16 + (threadIdx.x >> 4), c = threadIdx.x & 15;
  if (c < NCLS) {
    const float* hr = Hh + (size_t)r*HIDDIM;
    const float* wr = w2 + (size_t)c*HIDDIM;
    float acc = 0.f;
    for (int k = 0; k < HIDDIM; k += 4) {
      float4 hv = *(const float4*)(hr+k);
      float4 wv = *(const float4*)(wr+k);
      acc += hv.x*wv.x + hv.y*wv.y + hv.z*wv.z + hv.w*wv.w;
    }
    out[(size_t)r*NCLS + c] = acc + b2[c];
  }
}

extern "C" void kernel_launch(void* const* d_in, const int* in_sizes, int n_in,
                              void* d_out, int out_size, void* d_ws, size_t ws_size,
                              hipStream_t stream)
{
  const float* x      = (const float*)d_in[0];
  const float* proj_w = (const float*)d_in[1];
  const float* proj_b = (const float*)d_in[2];
  const float* cls    = (const float*)d_in[3];
  const float* pos    = (const float*)d_in[4];
  const float* wq     = (const float*)d_in[5];
  const float* bq     = (const float*)d_in[6];
  const float* wo     = (const float*)d_in[7];
  const float* bo     = (const float*)d_in[8];
  const float* w1     = (const float*)d_in[9];
  const float* b1     = (const float*)d_in[10];
  const float* w2     = (const float*)d_in[11];
  const float* b2     = (const float*)d_in[12];
  float* out = (float*)d_out;

  // workspace layout (floats): Wc 24576 | qbias 33280 | mh0 1M | ct 1M | hh 2M  (~16.2 MB)
  float* Wc    = (float*)d_ws;
  float* qbias = Wc + NHEADS*HD*PFEAT;
  float* mh0   = qbias + NHEADS*SEQL*HD;
  float* ct    = mh0 + (size_t)BATCH*EMB;
  float* hh    = ct  + (size_t)BATCH*EMB;

  hipLaunchKernelGGL(k_wc,    dim3(96),  dim3(256), 0, stream, wq, proj_w, Wc);
  hipLaunchKernelGGL(k_qbias, dim3(130), dim3(256), 0, stream, wq, bq, cls, pos, proj_b, qbias);
  hipLaunchKernelGGL(k_attn,  dim3(BATCH*NHEADS), dim3(256), 0, stream, x, Wc, qbias, mh0);
  hipLaunchKernelGGL((k_ffn<false>), dim3(BATCH/64, EMB/64),    dim3(256), 0, stream, mh0, wo, bo, ct, EMB, EMB);
  hipLaunchKernelGGL((k_ffn<true>),  dim3(BATCH/64, HIDDIM/64), dim3(256), 0, stream, ct, w1, b1, hh, HIDDIM, EMB);
  hipLaunchKernelGGL(k_logits, dim3(BATCH/16), dim3(256), 0, stream, hh, w2, b2, out);
}

// Round 3
// 604.218 us; speedup vs baseline: 1.2423x; 1.2423x over previous
//
#include <hip/hip_runtime.h>
#include <math.h>

#define BATCH 2048
#define SEQL 65
#define EMB 512
#define NHEADS 8
#define HD 64
#define NPATCH 64
#define PFEAT 48
#define HIDDIM 1024
#define NCLS 10

typedef short bfrag __attribute__((ext_vector_type(8)));   // 8 bf16 (4 VGPRs)
typedef float facc  __attribute__((ext_vector_type(16)));  // 16 f32 acc

__device__ inline unsigned short f2bf(float f) {
  unsigned int u = __float_as_uint(f);
  unsigned int r = (u + 0x7FFFu + ((u >> 16) & 1u)) >> 16;
  return (unsigned short)r;
}
__device__ inline float bf2f(unsigned short h) {
  return __uint_as_float(((unsigned int)h) << 16);
}
// load 8 consecutive bf16 (as shorts) from LDS, 8B-aligned -> 2x ds_read_b64
__device__ inline bfrag ldf(const unsigned short* p) {
  union { unsigned long long u[2]; bfrag s; } c;
  c.u[0] = *(const unsigned long long*)(p);
  c.u[1] = *(const unsigned long long*)(p + 4);
  return c.s;
}

// ---- K0a: Wc[h*64+k][f] = sum_d wq[h,k,d] * proj_w[d,f]  (512x48) ----
__global__ __launch_bounds__(256) void k_wc(
    const float* __restrict__ wq, const float* __restrict__ proj_w,
    float* __restrict__ Wc)
{
  int idx = blockIdx.x*256 + threadIdx.x;
  int hk = idx / PFEAT, f = idx - hk*PFEAT;
  const float* wr = wq + (size_t)hk*EMB;
  float acc = 0.f;
  for (int d = 0; d < EMB; ++d) acc += wr[d]*proj_w[d*PFEAT + f];
  Wc[idx] = acc;
}

// ---- K0b: qbias[h][s][k] = sum_d (pos[s,d] + (s? proj_b : cls)[d]) * wq[h,k,d] + bq[h,k] ----
__global__ __launch_bounds__(256) void k_qbias(
    const float* __restrict__ wq, const float* __restrict__ bq,
    const float* __restrict__ cls, const float* __restrict__ pos,
    const float* __restrict__ proj_b, float* __restrict__ qbias)
{
  int idx = blockIdx.x*256 + threadIdx.x;
  int h = idx / (SEQL*HD); int rem = idx - h*SEQL*HD;
  int s = rem / HD, k = rem - s*HD;
  const float* wr = wq + ((size_t)h*HD + k)*EMB;
  const float* po = pos + (size_t)s*EMB;
  float acc = bq[h*HD + k];
  if (s == 0) { for (int d = 0; d < EMB; ++d) acc += (po[d] + cls[d])   *wr[d]; }
  else        { for (int d = 0; d < EMB; ++d) acc += (po[d] + proj_b[d])*wr[d]; }
  qbias[idx] = acc;
}

// ---- K1: per (b,h): MFMA split-bf16 q-GEMM + S-GEMM, col softmax, att row0 -> mh0 ----
// LDS layout (bytes):
//   [0 .. 26624)   : Ph[64*52] Pl Wh Wl (ushort)   -- stage1; overlaid later by:
//                    S[65*66] f32 | pmax[260] | psum[260] | p0[65] | attp[256]
//   [26624..52736) : Qh[96*68] Ql[96*68] (ushort)
__global__ __launch_bounds__(256) void k_attn(
    const float* __restrict__ x, const float* __restrict__ Wc,
    const float* __restrict__ qbias, float* __restrict__ mh0)
{
  __shared__ __align__(16) char smem[52736];
  unsigned short* Ph = (unsigned short*)smem;          // 64*52
  unsigned short* Pl = Ph + 64*52;
  unsigned short* Wh = Pl + 64*52;
  unsigned short* Wl = Wh + 64*52;
  float* Sld  = (float*)smem;                          // 65*66 (overlay)
  float* pmax_ = Sld + 65*66;
  float* psum_ = pmax_ + 260;
  float* p0v   = psum_ + 260;
  float* attp  = p0v + 65;
  unsigned short* Qh = (unsigned short*)(smem + 26624); // 96*68
  unsigned short* Ql = Qh + 96*68;

  const int bh = blockIdx.x, b = bh >> 3, h = bh & 7;
  const int tid = threadIdx.x;
  const int w = tid >> 6, lane = tid & 63;
  const int ko = (lane >> 5) * 8;
  const float* xb = x + (size_t)b*3*32*32;
  const float* wch = Wc + (size_t)h*HD*PFEAT;
  const float* qb  = qbias + (size_t)h*SEQL*HD;

  // ---- stage LDS: patchify x_b (hi/lo) and W_h (hi/lo) ----
  for (int i = tid; i < NPATCH*PFEAT; i += 256) {
    int p = i / PFEAT, f = i - p*PFEAT;
    int ni = p >> 3, nj = p & 7;
    int c = f >> 4, r = f & 15, pi = r >> 2, pj = r & 3;
    float v = xb[c*1024 + (ni*4+pi)*32 + (nj*4+pj)];
    unsigned short hi = f2bf(v);
    Ph[p*52+f] = hi; Pl[p*52+f] = f2bf(v - bf2f(hi));
  }
  for (int i = tid; i < HD*PFEAT; i += 256) {
    int k = i / PFEAT, f = i - k*PFEAT;
    float v = wch[i];
    unsigned short hi = f2bf(v);
    Wh[k*52+f] = hi; Wl[k*52+f] = f2bf(v - bf2f(hi));
  }
  __syncthreads();

  // ---- stage 1: q[1+p][k] = P·W^T + qbias  (2x2 tiles of 32x32, K=48) ----
  {
    const int ti = w >> 1, tj = w & 1;
    const int ar = 32*ti + (lane & 31);
    const int br = 32*tj + (lane & 31);
    facc acc = {0,0,0,0,0,0,0,0,0,0,0,0,0,0,0,0};
    #pragma unroll
    for (int ks = 0; ks < 3; ++ks) {
      int f0 = ks*16 + ko;
      bfrag ah = ldf(Ph + ar*52 + f0), al = ldf(Pl + ar*52 + f0);
      bfrag bhh = ldf(Wh + br*52 + f0), bll = ldf(Wl + br*52 + f0);
      acc = __builtin_amdgcn_mfma_f32_32x32x16_bf16(ah, bhh, acc, 0, 0, 0);
      acc = __builtin_amdgcn_mfma_f32_32x32x16_bf16(ah, bll, acc, 0, 0, 0);
      acc = __builtin_amdgcn_mfma_f32_32x32x16_bf16(al, bhh, acc, 0, 0, 0);
    }
    #pragma unroll
    for (int r = 0; r < 16; ++r) {
      int row = (r & 3) + 8*(r >> 2) + 4*(lane >> 5) + 32*ti;  // patch row
      int col = 32*tj + (lane & 31);
      int s = 1 + row;
      float q = acc[r] + qb[s*HD + col];
      unsigned short hi = f2bf(q);
      Qh[s*68+col] = hi; Ql[s*68+col] = f2bf(q - bf2f(hi));
    }
    if (tid < HD) {        // cls row (s=0): pure bias
      float q = qb[tid];
      unsigned short hi = f2bf(q);
      Qh[tid] = hi; Ql[tid] = f2bf(q - bf2f(hi));
    }
  }
  __syncthreads();

  // ---- stage 2: S = Q·Q^T / 8  (3x3 tiles of 32x32 over 96-padded rows, K=64) ----
  for (int t = w; t < 9; t += 4) {
    const int si = (t / 3) * 32, sj = (t % 3) * 32;
    const int ar = si + (lane & 31);
    const int br = sj + (lane & 31);
    facc acc = {0,0,0,0,0,0,0,0,0,0,0,0,0,0,0,0};
    #pragma unroll
    for (int ks = 0; ks < 4; ++ks) {
      int k0 = ks*16 + ko;
      bfrag ah = ldf(Qh + ar*68 + k0), al = ldf(Ql + ar*68 + k0);
      bfrag bhh = ldf(Qh + br*68 + k0), bll = ldf(Ql + br*68 + k0);
      acc = __builtin_amdgcn_mfma_f32_32x32x16_bf16(ah, bhh, acc, 0, 0, 0);
      acc = __builtin_amdgcn_mfma_f32_32x32x16_bf16(ah, bll, acc, 0, 0, 0);
      acc = __builtin_amdgcn_mfma_f32_32x32x16_bf16(al, bhh, acc, 0, 0, 0);
    }
    #pragma unroll
    for (int r = 0; r < 16; ++r) {
      int row = si + (r & 3) + 8*(r >> 2) + 4*(lane >> 5);
      int col = sj + (lane & 31);
      if (row < SEQL && col < SEQL) Sld[row*66 + col] = acc[r] * 0.125f;
    }
  }
  __syncthreads();

  // ---- stage 3: column softmax (4 partial-threads per column) ----
  {
    const int p = tid & 3;
    const int s0 = p*17, s1 = (s0 + 17 < SEQL) ? s0 + 17 : SEQL;
    for (int c = tid >> 2; c < SEQL; c += 64) {
      float m = -1e30f;
      for (int s = s0; s < s1; ++s) m = fmaxf(m, Sld[s*66 + c]);
      pmax_[c*4 + p] = m;
    }
    __syncthreads();
    for (int c = tid >> 2; c < SEQL; c += 64) {
      float m = fmaxf(fmaxf(pmax_[c*4], pmax_[c*4+1]), fmaxf(pmax_[c*4+2], pmax_[c*4+3]));
      float sum = 0.f;
      for (int s = s0; s < s1; ++s) sum += expf(Sld[s*66 + c] - m);
      psum_[c*4 + p] = sum;
    }
    __syncthreads();
    if (tid < SEQL) {
      float m = fmaxf(fmaxf(pmax_[tid*4], pmax_[tid*4+1]), fmaxf(pmax_[tid*4+2], pmax_[tid*4+3]));
      float sum = psum_[tid*4] + psum_[tid*4+1] + psum_[tid*4+2] + psum_[tid*4+3];
      p0v[tid] = expf(Sld[tid] - m) / sum;   // row 0 of S
    }
  }
  __syncthreads();

  // ---- stage 4: att0[k] = sum_t p0[t]*q[t][k]  (4 partials per k) ----
  {
    const int k = tid & 63, p = tid >> 6;
    const int s0 = p*17, s1 = (s0 + 17 < SEQL) ? s0 + 17 : SEQL;
    float a = 0.f;
    for (int t = s0; t < s1; ++t)
      a += p0v[t] * (bf2f(Qh[t*68 + k]) + bf2f(Ql[t*68 + k]));
    attp[p*64 + k] = a;
  }
  __syncthreads();
  if (tid < 64) {
    float a = attp[tid] + attp[64+tid] + attp[128+tid] + attp[192+tid];
    mh0[(size_t)b*EMB + h*HD + tid] = a;
  }
}

// ---- K2/K3: C[M][N] = A[M][K] @ W[N][K]^T + bias (optional exact GELU) ----
template<bool GELU>
__global__ __launch_bounds__(256) void k_ffn(
    const float* __restrict__ A, const float* __restrict__ W,
    const float* __restrict__ bias, float* __restrict__ C, int N, int K)
{
  __shared__ float As2[16*65];
  __shared__ float Bs2[16*65];
  const int tid = threadIdx.x;
  const int m0 = blockIdx.x * 64, n0 = blockIdx.y * 64;
  const int tmr = (tid >> 4) & 15, tmc = tid & 15;
  const int lr = tid >> 2, lk = (tid & 3) << 2;
  float acc[4][4];
  #pragma unroll
  for (int i = 0; i < 4; ++i)
    #pragma unroll
    for (int j = 0; j < 4; ++j) acc[i][j] = 0.f;

  for (int k0 = 0; k0 < K; k0 += 16) {
    float4 a4 = *(const float4*)(A + (size_t)(m0+lr)*K + k0 + lk);
    float4 b4 = *(const float4*)(W + (size_t)(n0+lr)*K + k0 + lk);
    As2[(lk+0)*65+lr] = a4.x; As2[(lk+1)*65+lr] = a4.y; As2[(lk+2)*65+lr] = a4.z; As2[(lk+3)*65+lr] = a4.w;
    Bs2[(lk+0)*65+lr] = b4.x; Bs2[(lk+1)*65+lr] = b4.y; Bs2[(lk+2)*65+lr] = b4.z; Bs2[(lk+3)*65+lr] = b4.w;
    __syncthreads();
    #pragma unroll
    for (int kk = 0; kk < 16; ++kk) {
      float av[4], bv[4];
      #pragma unroll
      for (int i = 0; i < 4; ++i) av[i] = As2[kk*65 + tmr*4+i];
      #pragma unroll
      for (int j = 0; j < 4; ++j) bv[j] = Bs2[kk*65 + tmc*4+j];
      #pragma unroll
      for (int i = 0; i < 4; ++i)
        #pragma unroll
        for (int j = 0; j < 4; ++j) acc[i][j] += av[i]*bv[j];
    }
    __syncthreads();
  }
  #pragma unroll
  for (int i = 0; i < 4; ++i) {
    #pragma unroll
    for (int j = 0; j < 4; ++j) {
      int m = m0 + tmr*4+i, n = n0 + tmc*4+j;
      float c = acc[i][j] + bias[n];
      if (GELU) c = 0.5f*c*(1.f + erff(c*0.70710678118654752f));
      C[(size_t)m*N + n] = c;
    }
  }
}

// ---- K4: logits = H @ w2^T + b2 ----
__global__ __launch_bounds__(256) void k_logits(
    const float* __restrict__ Hh, const float* __restrict__ w2,
    const float* __restrict__ b2, float* __restrict__ out)
{
  const int r = blockIdx.x*16 + (threadIdx.x >> 4), c = threadIdx.x & 15;
  if (c < NCLS) {
    const float* hr = Hh + (size_t)r*HIDDIM;
    const float* wr = w2 + (size_t)c*HIDDIM;
    float acc = 0.f;
    for (int k = 0; k < HIDDIM; k += 4) {
      float4 hv = *(const float4*)(hr+k);
      float4 wv = *(const float4*)(wr+k);
      acc += hv.x*wv.x + hv.y*wv.y + hv.z*wv.z + hv.w*wv.w;
    }
    out[(size_t)r*NCLS + c] = acc + b2[c];
  }
}

extern "C" void kernel_launch(void* const* d_in, const int* in_sizes, int n_in,
                              void* d_out, int out_size, void* d_ws, size_t ws_size,
                              hipStream_t stream)
{
  const float* x      = (const float*)d_in[0];
  const float* proj_w = (const float*)d_in[1];
  const float* proj_b = (const float*)d_in[2];
  const float* cls    = (const float*)d_in[3];
  const float* pos    = (const float*)d_in[4];
  const float* wq     = (const float*)d_in[5];
  const float* bq     = (const float*)d_in[6];
  const float* wo     = (const float*)d_in[7];
  const float* bo     = (const float*)d_in[8];
  const float* w1     = (const float*)d_in[9];
  const float* b1     = (const float*)d_in[10];
  const float* w2     = (const float*)d_in[11];
  const float* b2     = (const float*)d_in[12];
  float* out = (float*)d_out;

  float* Wc    = (float*)d_ws;                 // 512*48
  float* qbias = Wc + NHEADS*HD*PFEAT;         // 8*65*64
  float* mh0   = qbias + NHEADS*SEQL*HD;       // B*512
  float* ct    = mh0 + (size_t)BATCH*EMB;      // B*512
  float* hh    = ct  + (size_t)BATCH*EMB;      // B*1024

  hipLaunchKernelGGL(k_wc,    dim3(96),  dim3(256), 0, stream, wq, proj_w, Wc);
  hipLaunchKernelGGL(k_qbias, dim3(130), dim3(256), 0, stream, wq, bq, cls, pos, proj_b, qbias);
  hipLaunchKernelGGL(k_attn,  dim3(BATCH*NHEADS), dim3(256), 0, stream, x, Wc, qbias, mh0);
  hipLaunchKernelGGL((k_ffn<false>), dim3(BATCH/64, EMB/64),    dim3(256), 0, stream, mh0, wo, bo, ct, EMB, EMB);
  hipLaunchKernelGGL((k_ffn<true>),  dim3(BATCH/64, HIDDIM/64), dim3(256), 0, stream, ct, w1, b1, hh, HIDDIM, EMB);
  hipLaunchKernelGGL(k_logits, dim3(BATCH/16), dim3(256), 0, stream, hh, w2, b2, out);
}

// Round 4
// 477.264 us; speedup vs baseline: 1.5728x; 1.2660x over previous
//
#include <hip/hip_runtime.h>
#include <math.h>

#define BATCH 2048
#define SEQL 65
#define EMB 512
#define NHEADS 8
#define HD 64
#define NPATCH 64
#define PFEAT 48
#define HIDDIM 1024
#define NCLS 10

typedef short bfrag __attribute__((ext_vector_type(8)));   // 8 bf16 (4 VGPRs)
typedef float facc  __attribute__((ext_vector_type(16)));  // 16 f32 acc

__device__ inline unsigned short f2bf(float f) {
  unsigned int u = __float_as_uint(f);
  unsigned int r = (u + 0x7FFFu + ((u >> 16) & 1u)) >> 16;
  return (unsigned short)r;
}
__device__ inline float bf2f(unsigned short h) {
  return __uint_as_float(((unsigned int)h) << 16);
}
__device__ inline bfrag ldf(const unsigned short* p) {   // LDS: 2x ds_read_b64
  union { unsigned long long u[2]; bfrag s; } c;
  c.u[0] = *(const unsigned long long*)(p);
  c.u[1] = *(const unsigned long long*)(p + 4);
  return c.s;
}
__device__ inline unsigned long long pack4(unsigned short a, unsigned short b,
                                           unsigned short c, unsigned short d) {
  return (unsigned long long)a | ((unsigned long long)b << 16) |
         ((unsigned long long)c << 32) | ((unsigned long long)d << 48);
}

// ---- K0a: Wc = wq @ proj_w, packed to bf16 hi/lo [512][48] ----
__global__ __launch_bounds__(256) void k_pack(
    const float* __restrict__ wq, const float* __restrict__ proj_w,
    unsigned short* __restrict__ WcH, unsigned short* __restrict__ WcL)
{
  __shared__ float wr[EMB];
  __shared__ float part[PFEAT*4];
  const int hk = blockIdx.x, tid = threadIdx.x;
  wr[tid] = wq[(size_t)hk*EMB + tid];
  wr[256+tid] = wq[(size_t)hk*EMB + 256 + tid];
  __syncthreads();
  if (tid < PFEAT*4) {
    int f = tid >> 2, p = tid & 3;
    float a = 0.f;
    for (int d = p*128; d < (p+1)*128; ++d) a += wr[d]*proj_w[d*PFEAT + f];
    part[tid] = a;
  }
  __syncthreads();
  if (tid < PFEAT) {
    float v = part[tid*4] + part[tid*4+1] + part[tid*4+2] + part[tid*4+3];
    unsigned short hi = f2bf(v);
    WcH[hk*PFEAT + tid] = hi;
    WcL[hk*PFEAT + tid] = f2bf(v - bf2f(hi));
  }
}

// ---- K0b: qbias[h][s][k] = (pos[s] + (s? proj_b : cls)) . wq[h,k,:] + bq[h,k] ----
__global__ __launch_bounds__(256) void k_qbias(
    const float* __restrict__ wq, const float* __restrict__ bq,
    const float* __restrict__ cls, const float* __restrict__ pos,
    const float* __restrict__ proj_b, float* __restrict__ qbias)
{
  __shared__ float v[EMB];
  __shared__ float part[HD*4];
  const int h = blockIdx.x / SEQL, s = blockIdx.x - h*SEQL;
  const int tid = threadIdx.x;
  const float* po = pos + (size_t)s*EMB;
  v[tid]     = po[tid]     + (s == 0 ? cls[tid]     : proj_b[tid]);
  v[256+tid] = po[256+tid] + (s == 0 ? cls[256+tid] : proj_b[256+tid]);
  __syncthreads();
  {
    int k = tid >> 2, p = tid & 3;
    const float* wrr = wq + ((size_t)h*HD + k)*EMB + p*128;
    const float* vv = v + p*128;
    float a = 0.f;
    for (int i = 0; i < 128; ++i) a += vv[i]*wrr[i];
    part[tid] = a;
  }
  __syncthreads();
  if (tid < HD)
    qbias[((size_t)h*SEQL + s)*HD + tid] =
        part[tid*4] + part[tid*4+1] + part[tid*4+2] + part[tid*4+3] + bq[h*HD + tid];
}

// ---- K1: block = image b; loop 8 heads. MFMA split-bf16, symmetric S, row softmax ----
// LDS: Ph[64*52] Pl | Qh[65*68] Ql | S[65*66]f32 | pmax[260] psum[260] p0[65] attp[256]
__global__ __launch_bounds__(256) void k_attn(
    const float* __restrict__ x, const unsigned short* __restrict__ WcH,
    const unsigned short* __restrict__ WcL, const float* __restrict__ qbias,
    float* __restrict__ mh0)
{
  __shared__ __align__(16) char smem[51520];
  unsigned short* Ph = (unsigned short*)smem;              // 64*52
  unsigned short* Pl = Ph + 64*52;
  unsigned short* Qh = (unsigned short*)(smem + 13312);    // 65*68
  unsigned short* Ql = Qh + SEQL*68;
  float* S     = (float*)(smem + 30992);                   // 65*66
  float* pmax_ = (float*)(smem + 48152);
  float* psum_ = (float*)(smem + 49192);
  float* p0v   = (float*)(smem + 50232);
  float* attp  = (float*)(smem + 50492);

  const int b = blockIdx.x, tid = threadIdx.x;
  const int w = tid >> 6, lane = tid & 63;
  const int ko = (lane >> 5) * 8;
  const float* xb = x + (size_t)b*3*32*32;

  // ---- patchify once (float4 loads, hi/lo split) ----
  for (int i = tid; i < NPATCH*12; i += 256) {
    int p = i / 12, fq = i - p*12;
    int c = fq >> 2, pi = fq & 3;
    int ni = p >> 3, nj = p & 7;
    float4 v = *(const float4*)(xb + c*1024 + (ni*4+pi)*32 + nj*4);
    int f = c*16 + pi*4;
    unsigned short h0 = f2bf(v.x), h1 = f2bf(v.y), h2 = f2bf(v.z), h3 = f2bf(v.w);
    *(unsigned long long*)(Ph + p*52 + f) = pack4(h0, h1, h2, h3);
    *(unsigned long long*)(Pl + p*52 + f) =
        pack4(f2bf(v.x - bf2f(h0)), f2bf(v.y - bf2f(h1)),
              f2bf(v.z - bf2f(h2)), f2bf(v.w - bf2f(h3)));
  }
  __syncthreads();

  for (int h = 0; h < NHEADS; ++h) {
    const float* qb = qbias + (size_t)h*SEQL*HD;
    // ---- stage 1: q = P·Wc^T + qbias (2x2 tiles 32x32, K=48, B from global) ----
    {
      const int ti = w >> 1, tj = w & 1;
      const int ar = 32*ti + (lane & 31);
      const int br = 32*tj + (lane & 31);
      const unsigned short* wbase = WcH + ((size_t)h*HD + br)*PFEAT;
      const unsigned short* wlbase = WcL + ((size_t)h*HD + br)*PFEAT;
      facc acc = {0,0,0,0,0,0,0,0,0,0,0,0,0,0,0,0};
      #pragma unroll
      for (int ks = 0; ks < 3; ++ks) {
        int f0 = ks*16 + ko;
        bfrag ah = ldf(Ph + ar*52 + f0), al = ldf(Pl + ar*52 + f0);
        bfrag bh = *(const bfrag*)(wbase + f0);
        bfrag bl = *(const bfrag*)(wlbase + f0);
        acc = __builtin_amdgcn_mfma_f32_32x32x16_bf16(ah, bh, acc, 0, 0, 0);
        acc = __builtin_amdgcn_mfma_f32_32x32x16_bf16(ah, bl, acc, 0, 0, 0);
        acc = __builtin_amdgcn_mfma_f32_32x32x16_bf16(al, bh, acc, 0, 0, 0);
      }
      #pragma unroll
      for (int r = 0; r < 16; ++r) {
        int row = (r & 3) + 8*(r >> 2) + 4*(lane >> 5) + 32*ti;
        int col = 32*tj + (lane & 31);
        int s = 1 + row;
        float q = acc[r] + qb[s*HD + col];
        unsigned short hi = f2bf(q);
        Qh[s*68+col] = hi; Ql[s*68+col] = f2bf(q - bf2f(hi));
      }
      if (tid < HD) {
        float q = qb[tid];
        unsigned short hi = f2bf(q);
        Qh[tid] = hi; Ql[tid] = f2bf(q - bf2f(hi));
      }
    }
    __syncthreads();   // A

    // ---- stage 2: S upper triangle via 3 MFMA tiles; row/col 64 on wave 3 ----
    if (w < 3) {
      const int ti2 = (w == 1) ? 1 : 0;
      const int tj2 = (w == 0) ? 0 : 1;
      const int ar = 32*ti2 + (lane & 31);
      const int br = 32*tj2 + (lane & 31);
      facc acc = {0,0,0,0,0,0,0,0,0,0,0,0,0,0,0,0};
      #pragma unroll
      for (int ks = 0; ks < 4; ++ks) {
        int k0 = ks*16 + ko;
        bfrag ah = ldf(Qh + ar*68 + k0), al = ldf(Ql + ar*68 + k0);
        bfrag bh = ldf(Qh + br*68 + k0), bl = ldf(Ql + br*68 + k0);
        acc = __builtin_amdgcn_mfma_f32_32x32x16_bf16(ah, bh, acc, 0, 0, 0);
        acc = __builtin_amdgcn_mfma_f32_32x32x16_bf16(ah, bl, acc, 0, 0, 0);
        acc = __builtin_amdgcn_mfma_f32_32x32x16_bf16(al, bh, acc, 0, 0, 0);
      }
      #pragma unroll
      for (int r = 0; r < 16; ++r) {
        int row = 32*ti2 + (r & 3) + 8*(r >> 2) + 4*(lane >> 5);
        int col = 32*tj2 + (lane & 31);
        float sv = acc[r] * 0.125f;
        S[row*66 + col] = sv;
        if (w == 2) S[col*66 + row] = sv;   // mirror off-diagonal tile
      }
    } else {
      // wave 3: S[64][t] = q64·qt / 8 (and mirror)
      for (int t = lane; t < SEQL; t += 64) {
        float a = 0.f;
        #pragma unroll 8
        for (int k2 = 0; k2 < HD; ++k2) {
          float q64 = bf2f(Qh[64*68+k2]) + bf2f(Ql[64*68+k2]);
          float qt  = bf2f(Qh[t*68+k2])  + bf2f(Ql[t*68+k2]);
          a += q64*qt;
        }
        a *= 0.125f;
        S[64*66 + t] = a;
        if (t < 64) S[t*66 + 64] = a;
      }
    }
    __syncthreads();   // B

    // ---- softmax over rows (== columns by symmetry), 4 partials per row ----
    {
      int r = tid >> 2, p = tid & 3;
      int c0 = p*17, c1 = (c0 + 17 < SEQL) ? c0 + 17 : SEQL;
      for (int row = r; row < SEQL; row += 64) {
        float m = -1e30f;
        for (int c = c0; c < c1; ++c) m = fmaxf(m, S[row*66 + c]);
        pmax_[row*4 + p] = m;
      }
    }
    __syncthreads();   // C1
    {
      int r = tid >> 2, p = tid & 3;
      int c0 = p*17, c1 = (c0 + 17 < SEQL) ? c0 + 17 : SEQL;
      for (int row = r; row < SEQL; row += 64) {
        float m = fmaxf(fmaxf(pmax_[row*4], pmax_[row*4+1]),
                        fmaxf(pmax_[row*4+2], pmax_[row*4+3]));
        float sum = 0.f;
        for (int c = c0; c < c1; ++c) sum += __expf(S[row*66 + c] - m);
        psum_[row*4 + p] = sum;
      }
    }
    __syncthreads();   // C2
    if (tid < SEQL) {
      float m = fmaxf(fmaxf(pmax_[tid*4], pmax_[tid*4+1]),
                      fmaxf(pmax_[tid*4+2], pmax_[tid*4+3]));
      float sum = psum_[tid*4] + psum_[tid*4+1] + psum_[tid*4+2] + psum_[tid*4+3];
      p0v[tid] = __expf(S[tid*66] - m) / sum;
    }
    __syncthreads();   // D

    // ---- att0[k] = sum_t p0[t]*q[t][k] (4 partials) ----
    {
      int k = tid & 63, p = tid >> 6;
      int t0 = p*17, t1 = (t0 + 17 < SEQL) ? t0 + 17 : SEQL;
      float a = 0.f;
      for (int t = t0; t < t1; ++t)
        a += p0v[t] * (bf2f(Qh[t*68 + k]) + bf2f(Ql[t*68 + k]));
      attp[p*64 + k] = a;
    }
    __syncthreads();   // E
    if (tid < HD)
      mh0[(size_t)b*EMB + h*HD + tid] =
          attp[tid] + attp[64+tid] + attp[128+tid] + attp[192+tid];
    // next head's Q writes are safely after barrier E (att0's Q reads precede it)
  }
}

// ---- K2/K3: C[M][N] = A[M][K] @ W[N][K]^T + bias (optional exact GELU) ----
template<bool GELU>
__global__ __launch_bounds__(256) void k_ffn(
    const float* __restrict__ A, const float* __restrict__ W,
    const float* __restrict__ bias, float* __restrict__ C, int N, int K)
{
  __shared__ float As2[16*65];
  __shared__ float Bs2[16*65];
  const int tid = threadIdx.x;
  const int m0 = blockIdx.x * 64, n0 = blockIdx.y * 64;
  const int tmr = (tid >> 4) & 15, tmc = tid & 15;
  const int lr = tid >> 2, lk = (tid & 3) << 2;
  float acc[4][4];
  #pragma unroll
  for (int i = 0; i < 4; ++i)
    #pragma unroll
    for (int j = 0; j < 4; ++j) acc[i][j] = 0.f;

  for (int k0 = 0; k0 < K; k0 += 16) {
    float4 a4 = *(const float4*)(A + (size_t)(m0+lr)*K + k0 + lk);
    float4 b4 = *(const float4*)(W + (size_t)(n0+lr)*K + k0 + lk);
    As2[(lk+0)*65+lr] = a4.x; As2[(lk+1)*65+lr] = a4.y; As2[(lk+2)*65+lr] = a4.z; As2[(lk+3)*65+lr] = a4.w;
    Bs2[(lk+0)*65+lr] = b4.x; Bs2[(lk+1)*65+lr] = b4.y; Bs2[(lk+2)*65+lr] = b4.z; Bs2[(lk+3)*65+lr] = b4.w;
    __syncthreads();
    #pragma unroll
    for (int kk = 0; kk < 16; ++kk) {
      float av[4], bv[4];
      #pragma unroll
      for (int i = 0; i < 4; ++i) av[i] = As2[kk*65 + tmr*4+i];
      #pragma unroll
      for (int j = 0; j < 4; ++j) bv[j] = Bs2[kk*65 + tmc*4+j];
      #pragma unroll
      for (int i = 0; i < 4; ++i)
        #pragma unroll
        for (int j = 0; j < 4; ++j) acc[i][j] += av[i]*bv[j];
    }
    __syncthreads();
  }
  #pragma unroll
  for (int i = 0; i < 4; ++i) {
    #pragma unroll
    for (int j = 0; j < 4; ++j) {
      int m = m0 + tmr*4+i, n = n0 + tmc*4+j;
      float c = acc[i][j] + bias[n];
      if (GELU) c = 0.5f*c*(1.f + erff(c*0.70710678118654752f));
      C[(size_t)m*N + n] = c;
    }
  }
}

// ---- K4: logits = H @ w2^T + b2 ----
__global__ __launch_bounds__(256) void k_logits(
    const float* __restrict__ Hh, const float* __restrict__ w2,
    const float* __restrict__ b2, float* __restrict__ out)
{
  const int r = blockIdx.x*16 + (threadIdx.x >> 4), c = threadIdx.x & 15;
  if (c < NCLS) {
    const float* hr = Hh + (size_t)r*HIDDIM;
    const float* wr = w2 + (size_t)c*HIDDIM;
    float acc = 0.f;
    for (int k = 0; k < HIDDIM; k += 4) {
      float4 hv = *(const float4*)(hr+k);
      float4 wv = *(const float4*)(wr+k);
      acc += hv.x*wv.x + hv.y*wv.y + hv.z*wv.z + hv.w*wv.w;
    }
    out[(size_t)r*NCLS + c] = acc + b2[c];
  }
}

extern "C" void kernel_launch(void* const* d_in, const int* in_sizes, int n_in,
                              void* d_out, int out_size, void* d_ws, size_t ws_size,
                              hipStream_t stream)
{
  const float* x      = (const float*)d_in[0];
  const float* proj_w = (const float*)d_in[1];
  const float* proj_b = (const float*)d_in[2];
  const float* cls    = (const float*)d_in[3];
  const float* pos    = (const float*)d_in[4];
  const float* wq     = (const float*)d_in[5];
  const float* bq     = (const float*)d_in[6];
  const float* wo     = (const float*)d_in[7];
  const float* bo     = (const float*)d_in[8];
  const float* w1     = (const float*)d_in[9];
  const float* b1     = (const float*)d_in[10];
  const float* w2     = (const float*)d_in[11];
  const float* b2     = (const float*)d_in[12];
  float* out = (float*)d_out;

  // ws layout (bytes): WcH 49152 | WcL 49152 | qbias 133120 | mh0 4MB | ct 4MB | hh 8MB
  unsigned short* WcH = (unsigned short*)d_ws;
  unsigned short* WcL = WcH + EMB*PFEAT;
  float* qbias = (float*)((char*)d_ws + 98304);
  float* mh0   = qbias + NHEADS*SEQL*HD;
  float* ct    = mh0 + (size_t)BATCH*EMB;
  float* hh    = ct  + (size_t)BATCH*EMB;

  hipLaunchKernelGGL(k_pack,  dim3(EMB), dim3(256), 0, stream, wq, proj_w, WcH, WcL);
  hipLaunchKernelGGL(k_qbias, dim3(NHEADS*SEQL), dim3(256), 0, stream, wq, bq, cls, pos, proj_b, qbias);
  hipLaunchKernelGGL(k_attn,  dim3(BATCH), dim3(256), 0, stream, x, WcH, WcL, qbias, mh0);
  hipLaunchKernelGGL((k_ffn<false>), dim3(BATCH/64, EMB/64),    dim3(256), 0, stream, mh0, wo, bo, ct, EMB, EMB);
  hipLaunchKernelGGL((k_ffn<true>),  dim3(BATCH/64, HIDDIM/64), dim3(256), 0, stream, ct, w1, b1, hh, HIDDIM, EMB);
  hipLaunchKernelGGL(k_logits, dim3(BATCH/16), dim3(256), 0, stream, hh, w2, b2, out);
}

// Round 5
// 393.184 us; speedup vs baseline: 1.9091x; 1.2138x over previous
//
#include <hip/hip_runtime.h>
#include <math.h>

#define BATCH 2048
#define SEQL 65
#define EMB 512
#define NHEADS 8
#define HD 64
#define NPATCH 64
#define PFEAT 48
#define HIDDIM 1024
#define NCLS 10

typedef short bfrag __attribute__((ext_vector_type(8)));   // 8 bf16 (4 VGPRs)
typedef float facc  __attribute__((ext_vector_type(16)));  // 16 f32 acc

__device__ inline unsigned short f2bf(float f) {
  unsigned int u = __float_as_uint(f);
  unsigned int r = (u + 0x7FFFu + ((u >> 16) & 1u)) >> 16;
  return (unsigned short)r;
}
__device__ inline float bf2f(unsigned short h) {
  return __uint_as_float(((unsigned int)h) << 16);
}
__device__ inline bfrag ldf(const unsigned short* p) {   // LDS: 2x ds_read_b64
  union { unsigned long long u[2]; bfrag s; } c;
  c.u[0] = *(const unsigned long long*)(p);
  c.u[1] = *(const unsigned long long*)(p + 4);
  return c.s;
}
__device__ inline unsigned long long pack4(unsigned short a, unsigned short b,
                                           unsigned short c, unsigned short d) {
  return (unsigned long long)a | ((unsigned long long)b << 16) |
         ((unsigned long long)c << 32) | ((unsigned long long)d << 48);
}

// ---- K0a: Wc = wq @ proj_w, packed to bf16 hi/lo [512][48] ----
__global__ __launch_bounds__(256) void k_pack(
    const float* __restrict__ wq, const float* __restrict__ proj_w,
    unsigned short* __restrict__ WcH, unsigned short* __restrict__ WcL)
{
  __shared__ float wr[EMB];
  __shared__ float part[PFEAT*4];
  const int hk = blockIdx.x, tid = threadIdx.x;
  wr[tid] = wq[(size_t)hk*EMB + tid];
  wr[256+tid] = wq[(size_t)hk*EMB + 256 + tid];
  __syncthreads();
  if (tid < PFEAT*4) {
    int f = tid >> 2, p = tid & 3;
    float a = 0.f;
    for (int d = p*128; d < (p+1)*128; ++d) a += wr[d]*proj_w[d*PFEAT + f];
    part[tid] = a;
  }
  __syncthreads();
  if (tid < PFEAT) {
    float v = part[tid*4] + part[tid*4+1] + part[tid*4+2] + part[tid*4+3];
    unsigned short hi = f2bf(v);
    WcH[hk*PFEAT + tid] = hi;
    WcL[hk*PFEAT + tid] = f2bf(v - bf2f(hi));
  }
}

// ---- K0b: qbias[h][s][k] = (pos[s] + (s? proj_b : cls)) . wq[h,k,:] + bq[h,k] ----
__global__ __launch_bounds__(256) void k_qbias(
    const float* __restrict__ wq, const float* __restrict__ bq,
    const float* __restrict__ cls, const float* __restrict__ pos,
    const float* __restrict__ proj_b, float* __restrict__ qbias)
{
  __shared__ float v[EMB];
  __shared__ float part[HD*4];
  const int h = blockIdx.x / SEQL, s = blockIdx.x - h*SEQL;
  const int tid = threadIdx.x;
  const float* po = pos + (size_t)s*EMB;
  v[tid]     = po[tid]     + (s == 0 ? cls[tid]     : proj_b[tid]);
  v[256+tid] = po[256+tid] + (s == 0 ? cls[256+tid] : proj_b[256+tid]);
  __syncthreads();
  {
    int k = tid >> 2, p = tid & 3;
    const float* wrr = wq + ((size_t)h*HD + k)*EMB + p*128;
    const float* vv = v + p*128;
    float a = 0.f;
    for (int i = 0; i < 128; ++i) a += vv[i]*wrr[i];
    part[tid] = a;
  }
  __syncthreads();
  if (tid < HD)
    qbias[((size_t)h*SEQL + s)*HD + tid] =
        part[tid*4] + part[tid*4+1] + part[tid*4+2] + part[tid*4+3] + bq[h*HD + tid];
}

// ---- K0c: generic f32 -> bf16 hi/lo packer (wo, w1) ----
__global__ __launch_bounds__(256) void k_packw(
    const float* __restrict__ src, unsigned short* __restrict__ dH,
    unsigned short* __restrict__ dL, int n)
{
  int i = blockIdx.x*256 + threadIdx.x;
  if (i < n) {
    float v = src[i];
    unsigned short hi = f2bf(v);
    dH[i] = hi; dL[i] = f2bf(v - bf2f(hi));
  }
}

// ---- K1: block per (b,h). MFMA split-bf16; S overlays P; symmetric S; row softmax ----
// LDS: [0,17408): Ph[64*52] Pl[64*52] (stage1) -> S[65*66] f32 (stage2+)
//      [17408,35088): Qh[65*68] Ql[65*68]
//      [35088,38464): pmax[260] psum[260] p0[68] attp[256]
__global__ __launch_bounds__(256) void k_attn(
    const float* __restrict__ x, const unsigned short* __restrict__ WcH,
    const unsigned short* __restrict__ WcL, const float* __restrict__ qbias,
    float* __restrict__ mh0)
{
  __shared__ __align__(16) char smem[38464];
  unsigned short* Ph = (unsigned short*)smem;              // 64*52
  unsigned short* Pl = Ph + 64*52;
  float* S = (float*)smem;                                 // 65*66 overlay
  unsigned short* Qh = (unsigned short*)(smem + 17408);    // 65*68
  unsigned short* Ql = Qh + SEQL*68;
  float* pmax_ = (float*)(smem + 35088);
  float* psum_ = (float*)(smem + 36128);
  float* p0v   = (float*)(smem + 37168);
  float* attp  = (float*)(smem + 37440);

  const int b = blockIdx.x >> 3, h = blockIdx.x & 7;
  const int tid = threadIdx.x, w = tid >> 6, lane = tid & 63;
  const int ko = (lane >> 5) * 8;
  const float* xb = x + (size_t)b*3072;
  const float* qb = qbias + (size_t)h*SEQL*HD;

  // ---- patchify (float4 loads, hi/lo split) ----
  for (int i = tid; i < NPATCH*12; i += 256) {
    int p = i / 12, fq = i - p*12;
    int c = fq >> 2, pi = fq & 3;
    int ni = p >> 3, nj = p & 7;
    float4 v = *(const float4*)(xb + c*1024 + (ni*4+pi)*32 + nj*4);
    int f = c*16 + pi*4;
    unsigned short h0 = f2bf(v.x), h1 = f2bf(v.y), h2 = f2bf(v.z), h3 = f2bf(v.w);
    *(unsigned long long*)(Ph + p*52 + f) = pack4(h0, h1, h2, h3);
    *(unsigned long long*)(Pl + p*52 + f) =
        pack4(f2bf(v.x - bf2f(h0)), f2bf(v.y - bf2f(h1)),
              f2bf(v.z - bf2f(h2)), f2bf(v.w - bf2f(h3)));
  }
  __syncthreads();

  // ---- stage 1: q = P·Wc_h^T + qbias (wave -> one 32x32 tile; B from global/L2) ----
  {
    const int ti = w >> 1, tj = w & 1;
    const int ar = 32*ti + (lane & 31);
    const int brk = h*HD + 32*tj + (lane & 31);
    const unsigned short* wb = WcH + (size_t)brk*PFEAT;
    const unsigned short* wl = WcL + (size_t)brk*PFEAT;
    facc acc = {0,0,0,0,0,0,0,0,0,0,0,0,0,0,0,0};
    #pragma unroll
    for (int ks = 0; ks < 3; ++ks) {
      int f0 = ks*16 + ko;
      bfrag ah = ldf(Ph + ar*52 + f0), al = ldf(Pl + ar*52 + f0);
      bfrag bh = *(const bfrag*)(wb + f0);
      bfrag bl = *(const bfrag*)(wl + f0);
      acc = __builtin_amdgcn_mfma_f32_32x32x16_bf16(ah, bh, acc, 0, 0, 0);
      acc = __builtin_amdgcn_mfma_f32_32x32x16_bf16(ah, bl, acc, 0, 0, 0);
      acc = __builtin_amdgcn_mfma_f32_32x32x16_bf16(al, bh, acc, 0, 0, 0);
    }
    #pragma unroll
    for (int r = 0; r < 16; ++r) {
      int row = (r & 3) + 8*(r >> 2) + 4*(lane >> 5) + 32*ti;
      int col = 32*tj + (lane & 31);
      int s = 1 + row;
      float q = acc[r] + qb[s*HD + col];
      unsigned short hi = f2bf(q);
      Qh[s*68+col] = hi; Ql[s*68+col] = f2bf(q - bf2f(hi));
    }
    if (tid < HD) {      // cls row s=0
      float q = qb[tid];
      unsigned short hi = f2bf(q);
      Qh[tid] = hi; Ql[tid] = f2bf(q - bf2f(hi));
    }
  }
  __syncthreads();   // A: P reads done; Q complete

  // ---- stage 2: S (symmetric) = Q·Q^T/8. waves 0-2: tiles (0,0),(1,1),(0,1)+mirror;
  //      wave 3: row/col 64 strip on VALU ----
  if (w < 3) {
    const int ti2 = (w == 1) ? 1 : 0;
    const int tj2 = (w == 0) ? 0 : 1;
    const int ar = 32*ti2 + (lane & 31);
    const int br = 32*tj2 + (lane & 31);
    facc acc = {0,0,0,0,0,0,0,0,0,0,0,0,0,0,0,0};
    #pragma unroll
    for (int ks = 0; ks < 4; ++ks) {
      int k0 = ks*16 + ko;
      bfrag ah = ldf(Qh + ar*68 + k0), al = ldf(Ql + ar*68 + k0);
      bfrag bh = ldf(Qh + br*68 + k0), bl = ldf(Ql + br*68 + k0);
      acc = __builtin_amdgcn_mfma_f32_32x32x16_bf16(ah, bh, acc, 0, 0, 0);
      acc = __builtin_amdgcn_mfma_f32_32x32x16_bf16(ah, bl, acc, 0, 0, 0);
      acc = __builtin_amdgcn_mfma_f32_32x32x16_bf16(al, bh, acc, 0, 0, 0);
    }
    #pragma unroll
    for (int r = 0; r < 16; ++r) {
      int row = 32*ti2 + (r & 3) + 8*(r >> 2) + 4*(lane >> 5);
      int col = 32*tj2 + (lane & 31);
      float sv = acc[r] * 0.125f;
      S[row*66 + col] = sv;
      if (w == 2) S[col*66 + row] = sv;
    }
  } else {
    for (int t = lane; t < SEQL; t += 64) {
      float a = 0.f;
      #pragma unroll 8
      for (int k2 = 0; k2 < HD; ++k2) {
        float q64 = bf2f(Qh[64*68+k2]) + bf2f(Ql[64*68+k2]);
        float qt  = bf2f(Qh[t*68+k2])  + bf2f(Ql[t*68+k2]);
        a += q64*qt;
      }
      a *= 0.125f;
      S[64*66 + t] = a;
      if (t < 64) S[t*66 + 64] = a;
    }
  }
  __syncthreads();   // B

  // ---- row softmax (== column by symmetry), 4 partials per row ----
  {
    int r = tid >> 2, p = tid & 3;
    int c0 = p*17, c1 = (c0 + 17 < SEQL) ? c0 + 17 : SEQL;
    for (int row = r; row < SEQL; row += 64) {
      float m = -1e30f;
      for (int c = c0; c < c1; ++c) m = fmaxf(m, S[row*66 + c]);
      pmax_[row*4 + p] = m;
    }
  }
  __syncthreads();   // C1
  {
    int r = tid >> 2, p = tid & 3;
    int c0 = p*17, c1 = (c0 + 17 < SEQL) ? c0 + 17 : SEQL;
    for (int row = r; row < SEQL; row += 64) {
      float m = fmaxf(fmaxf(pmax_[row*4], pmax_[row*4+1]),
                      fmaxf(pmax_[row*4+2], pmax_[row*4+3]));
      float sum = 0.f;
      for (int c = c0; c < c1; ++c) sum += __expf(S[row*66 + c] - m);
      psum_[row*4 + p] = sum;
    }
  }
  __syncthreads();   // C2
  if (tid < SEQL) {
    float m = fmaxf(fmaxf(pmax_[tid*4], pmax_[tid*4+1]),
                    fmaxf(pmax_[tid*4+2], pmax_[tid*4+3]));
    float sum = psum_[tid*4] + psum_[tid*4+1] + psum_[tid*4+2] + psum_[tid*4+3];
    p0v[tid] = __expf(S[tid*66] - m) / sum;   // S[t][0] == S[0][t]
  }
  __syncthreads();   // D

  // ---- att0[k] = sum_t p0[t]*q[t][k] (4 partials) ----
  {
    int k = tid & 63, p = tid >> 6;
    int t0 = p*17, t1 = (t0 + 17 < SEQL) ? t0 + 17 : SEQL;
    float a = 0.f;
    for (int t = t0; t < t1; ++t)
      a += p0v[t] * (bf2f(Qh[t*68 + k]) + bf2f(Ql[t*68 + k]));
    attp[p*64 + k] = a;
  }
  __syncthreads();   // E
  if (tid < HD)
    mh0[(size_t)b*EMB + h*HD + tid] =
        attp[tid] + attp[64+tid] + attp[128+tid] + attp[192+tid];
}

// ---- K2/K3: MFMA split-bf16 GEMM: C[M][N] = A_f32[M][K] @ Wpacked[N][K]^T + bias ----
template<bool GELU>
__global__ __launch_bounds__(256) void k_gemm(
    const float* __restrict__ A, const unsigned short* __restrict__ WH,
    const unsigned short* __restrict__ WL, const float* __restrict__ bias,
    float* __restrict__ C, int N, int K)
{
  __shared__ __align__(16) unsigned short Ah[64*36];
  __shared__ __align__(16) unsigned short Al[64*36];
  const int tid = threadIdx.x, w = tid >> 6, lane = tid & 63;
  const int ko = (lane >> 5) * 8;
  const int m0 = blockIdx.x*64, n0 = blockIdx.y*64;
  const int ti = w >> 1, tj = w & 1;
  const int ar = 32*ti + (lane & 31);
  const int nr = n0 + 32*tj + (lane & 31);
  const unsigned short* wh = WH + (size_t)nr*K;
  const unsigned short* wl = WL + (size_t)nr*K;
  const int srow = tid >> 2, skk = (tid & 3) * 8;
  facc acc = {0,0,0,0,0,0,0,0,0,0,0,0,0,0,0,0};

  for (int k0 = 0; k0 < K; k0 += 32) {
    const float* ap = A + (size_t)(m0+srow)*K + k0 + skk;
    float4 a0 = *(const float4*)(ap);
    float4 a1 = *(const float4*)(ap + 4);
    unsigned short h0 = f2bf(a0.x), h1 = f2bf(a0.y), h2 = f2bf(a0.z), h3 = f2bf(a0.w);
    unsigned short h4 = f2bf(a1.x), h5 = f2bf(a1.y), h6 = f2bf(a1.z), h7 = f2bf(a1.w);
    *(unsigned long long*)(Ah + srow*36 + skk)     = pack4(h0,h1,h2,h3);
    *(unsigned long long*)(Ah + srow*36 + skk + 4) = pack4(h4,h5,h6,h7);
    *(unsigned long long*)(Al + srow*36 + skk)     =
        pack4(f2bf(a0.x - bf2f(h0)), f2bf(a0.y - bf2f(h1)),
              f2bf(a0.z - bf2f(h2)), f2bf(a0.w - bf2f(h3)));
    *(unsigned long long*)(Al + srow*36 + skk + 4) =
        pack4(f2bf(a1.x - bf2f(h4)), f2bf(a1.y - bf2f(h5)),
              f2bf(a1.z - bf2f(h6)), f2bf(a1.w - bf2f(h7)));
    __syncthreads();
    #pragma unroll
    for (int ks = 0; ks < 2; ++ks) {
      int f0 = ks*16 + ko;
      bfrag ah = ldf(Ah + ar*36 + f0), al = ldf(Al + ar*36 + f0);
      bfrag bh = *(const bfrag*)(wh + k0 + f0);
      bfrag bl = *(const bfrag*)(wl + k0 + f0);
      acc = __builtin_amdgcn_mfma_f32_32x32x16_bf16(ah, bh, acc, 0, 0, 0);
      acc = __builtin_amdgcn_mfma_f32_32x32x16_bf16(ah, bl, acc, 0, 0, 0);
      acc = __builtin_amdgcn_mfma_f32_32x32x16_bf16(al, bh, acc, 0, 0, 0);
    }
    __syncthreads();
  }
  #pragma unroll
  for (int r = 0; r < 16; ++r) {
    int m = m0 + 32*ti + (r & 3) + 8*(r >> 2) + 4*(lane >> 5);
    float c = acc[r] + bias[nr];
    if (GELU) c = 0.5f*c*(1.f + erff(c*0.70710678118654752f));
    C[(size_t)m*N + nr] = c;
  }
}

// ---- K4: logits = H @ w2^T + b2 ----
__global__ __launch_bounds__(256) void k_logits(
    const float* __restrict__ Hh, const float* __restrict__ w2,
    const float* __restrict__ b2, float* __restrict__ out)
{
  const int r = blockIdx.x*16 + (threadIdx.x >> 4), c = threadIdx.x & 15;
  if (c < NCLS) {
    const float* hr = Hh + (size_t)r*HIDDIM;
    const float* wr = w2 + (size_t)c*HIDDIM;
    float acc = 0.f;
    for (int k = 0; k < HIDDIM; k += 4) {
      float4 hv = *(const float4*)(hr+k);
      float4 wv = *(const float4*)(wr+k);
      acc += hv.x*wv.x + hv.y*wv.y + hv.z*wv.z + hv.w*wv.w;
    }
    out[(size_t)r*NCLS + c] = acc + b2[c];
  }
}

extern "C" void kernel_launch(void* const* d_in, const int* in_sizes, int n_in,
                              void* d_out, int out_size, void* d_ws, size_t ws_size,
                              hipStream_t stream)
{
  const float* x      = (const float*)d_in[0];
  const float* proj_w = (const float*)d_in[1];
  const float* proj_b = (const float*)d_in[2];
  const float* cls    = (const float*)d_in[3];
  const float* pos    = (const float*)d_in[4];
  const float* wq     = (const float*)d_in[5];
  const float* bq     = (const float*)d_in[6];
  const float* wo     = (const float*)d_in[7];
  const float* bo     = (const float*)d_in[8];
  const float* w1     = (const float*)d_in[9];
  const float* b1     = (const float*)d_in[10];
  const float* w2     = (const float*)d_in[11];
  const float* b2     = (const float*)d_in[12];
  float* out = (float*)d_out;

  // ws layout (bytes):
  // WcH 0..49152 | WcL ..98304 | qbias ..231424 | WoH ..755712 | WoL ..1280000
  // | W1H ..2328576 | W1L ..3377152 | mh0 ..7571456 | ct ..11765760 | hh ..20154368
  unsigned short* WcH = (unsigned short*)d_ws;
  unsigned short* WcL = WcH + EMB*PFEAT;
  float* qbias = (float*)((char*)d_ws + 98304);
  unsigned short* WoH = (unsigned short*)((char*)d_ws + 231424);
  unsigned short* WoL = (unsigned short*)((char*)d_ws + 755712);
  unsigned short* W1H = (unsigned short*)((char*)d_ws + 1280000);
  unsigned short* W1L = (unsigned short*)((char*)d_ws + 2328576);
  float* mh0 = (float*)((char*)d_ws + 3377152);
  float* ct  = (float*)((char*)d_ws + 7571456);
  float* hh  = (float*)((char*)d_ws + 11765760);

  hipLaunchKernelGGL(k_pack,  dim3(EMB), dim3(256), 0, stream, wq, proj_w, WcH, WcL);
  hipLaunchKernelGGL(k_qbias, dim3(NHEADS*SEQL), dim3(256), 0, stream, wq, bq, cls, pos, proj_b, qbias);
  hipLaunchKernelGGL(k_packw, dim3(1024), dim3(256), 0, stream, wo, WoH, WoL, EMB*EMB);
  hipLaunchKernelGGL(k_packw, dim3(2048), dim3(256), 0, stream, w1, W1H, W1L, HIDDIM*EMB);
  hipLaunchKernelGGL(k_attn,  dim3(BATCH*NHEADS), dim3(256), 0, stream, x, WcH, WcL, qbias, mh0);
  hipLaunchKernelGGL((k_gemm<false>), dim3(BATCH/64, EMB/64),    dim3(256), 0, stream,
                     mh0, WoH, WoL, bo, ct, EMB, EMB);
  hipLaunchKernelGGL((k_gemm<true>),  dim3(BATCH/64, HIDDIM/64), dim3(256), 0, stream,
                     ct, W1H, W1L, b1, hh, HIDDIM, EMB);
  hipLaunchKernelGGL(k_logits, dim3(BATCH/16), dim3(256), 0, stream, hh, w2, b2, out);
}

// Round 6
// 321.555 us; speedup vs baseline: 2.3344x; 1.2228x over previous
//
#include <hip/hip_runtime.h>
#include <hip/hip_bf16.h>
#include <math.h>

#define BATCH 2048
#define SEQL 65
#define EMB 512
#define NHEADS 8
#define HD 64
#define NPATCH 64
#define PFEAT 48
#define HIDDIM 1024
#define NCLS 10

typedef short bfrag __attribute__((ext_vector_type(8)));   // 8 bf16 (4 VGPRs)
typedef float facc  __attribute__((ext_vector_type(16)));  // 16 f32 acc

union B8 { unsigned int u[4]; unsigned long long ull[2]; bfrag f; };

__device__ inline unsigned int cvt2(float a, float b) {     // 2x f32 -> packed bf16 (RTNE)
  __hip_bfloat162 t = __float22bfloat162_rn(float2{a, b});
  return *(unsigned int*)&t;
}
__device__ inline unsigned short f2bf(float f) {
  __hip_bfloat16 h = __float2bfloat16(f);
  return *(unsigned short*)&h;
}
__device__ inline float bf2f(unsigned short h) {
  return __uint_as_float(((unsigned int)h) << 16);
}
__device__ inline float lo16f(unsigned int u) { return __uint_as_float(u << 16); }
__device__ inline float hi16f(unsigned int u) { return __uint_as_float(u & 0xffff0000u); }
__device__ inline bfrag ldf(const unsigned short* p) {      // LDS: 2x ds_read_b64
  union { unsigned long long u[2]; bfrag s; } c;
  c.u[0] = *(const unsigned long long*)(p);
  c.u[1] = *(const unsigned long long*)(p + 4);
  return c.s;
}

// ---- K0a: Wc = wq @ proj_w, packed to bf16 hi/lo [512][48] ----
__global__ __launch_bounds__(256) void k_pack(
    const float* __restrict__ wq, const float* __restrict__ proj_w,
    unsigned short* __restrict__ WcH, unsigned short* __restrict__ WcL)
{
  __shared__ float wr[EMB];
  __shared__ float part[PFEAT*4];
  const int hk = blockIdx.x, tid = threadIdx.x;
  wr[tid] = wq[(size_t)hk*EMB + tid];
  wr[256+tid] = wq[(size_t)hk*EMB + 256 + tid];
  __syncthreads();
  if (tid < PFEAT*4) {
    int f = tid >> 2, p = tid & 3;
    float a = 0.f;
    for (int d = p*128; d < (p+1)*128; ++d) a += wr[d]*proj_w[d*PFEAT + f];
    part[tid] = a;
  }
  __syncthreads();
  if (tid < PFEAT) {
    float v = part[tid*4] + part[tid*4+1] + part[tid*4+2] + part[tid*4+3];
    unsigned short hi = f2bf(v);
    WcH[hk*PFEAT + tid] = hi;
    WcL[hk*PFEAT + tid] = f2bf(v - bf2f(hi));
  }
}

// ---- K0b: qbias[h][s][k] = (pos[s] + (s? proj_b : cls)) . wq[h,k,:] + bq[h,k] ----
__global__ __launch_bounds__(256) void k_qbias(
    const float* __restrict__ wq, const float* __restrict__ bq,
    const float* __restrict__ cls, const float* __restrict__ pos,
    const float* __restrict__ proj_b, float* __restrict__ qbias)
{
  __shared__ float v[EMB];
  __shared__ float part[HD*4];
  const int h = blockIdx.x / SEQL, s = blockIdx.x - h*SEQL;
  const int tid = threadIdx.x;
  const float* po = pos + (size_t)s*EMB;
  v[tid]     = po[tid]     + (s == 0 ? cls[tid]     : proj_b[tid]);
  v[256+tid] = po[256+tid] + (s == 0 ? cls[256+tid] : proj_b[256+tid]);
  __syncthreads();
  {
    int k = tid >> 2, p = tid & 3;
    const float* wrr = wq + ((size_t)h*HD + k)*EMB + p*128;
    const float* vv = v + p*128;
    float a = 0.f;
    for (int i = 0; i < 128; ++i) a += vv[i]*wrr[i];
    part[tid] = a;
  }
  __syncthreads();
  if (tid < HD)
    qbias[((size_t)h*SEQL + s)*HD + tid] =
        part[tid*4] + part[tid*4+1] + part[tid*4+2] + part[tid*4+3] + bq[h*HD + tid];
}

// ---- K0c: generic f32 -> bf16 hi/lo packer (wo, w1) ----
__global__ __launch_bounds__(256) void k_packw(
    const float* __restrict__ src, unsigned short* __restrict__ dH,
    unsigned short* __restrict__ dL, int n)
{
  int i = blockIdx.x*256 + threadIdx.x;
  if (i < n) {
    float v = src[i];
    unsigned short hi = f2bf(v);
    dH[i] = hi; dL[i] = f2bf(v - bf2f(hi));
  }
}

// ---- K1: block per (b,h), id = h*2048+b (same-b blocks share an XCD).
// Stage1: A-frags direct from global x (P never staged); split-bf16 MFMA; Q -> bf16 LDS.
// Stage2: Q zero-padded to 96 rows; 9 MFMA 32x32 tiles (no serial strip).
// LDS: Qh[96*68]u16 | S[65*66]f32 | pmax[260] psum[260] p0[68] (attp overlays pmax)
__global__ __launch_bounds__(256) void k_attn(
    const float* __restrict__ x, const unsigned short* __restrict__ WcH,
    const unsigned short* __restrict__ WcL, const float* __restrict__ qbias,
    float* __restrict__ mh0)
{
  __shared__ __align__(16) char smem[32568];
  unsigned short* Qh = (unsigned short*)smem;           // 96*68 u16 = 13056 B
  float* S     = (float*)(smem + 13056);                // 65*66*4 = 17160 -> 30216
  float* pmax_ = (float*)(smem + 30216);                // 1040
  float* psum_ = (float*)(smem + 31256);                // 1040
  float* p0v   = (float*)(smem + 32296);                // 272
  float* attp  = (float*)(smem + 30216);                // overlay pmax (dead after D)

  const int b = blockIdx.x & 2047, h = blockIdx.x >> 11;
  const int tid = threadIdx.x, w = tid >> 6, lane = tid & 63;
  const int u2 = lane >> 5;            // k-fragment half (0/1)
  const float* xb = x + (size_t)b*3072;
  const float* qb = qbias + (size_t)h*SEQL*HD;

  // ---- stage 1: q = P·Wc_h^T + qbias; A from global, B from global/L2 ----
  {
    const int ti = w >> 1, tj = w & 1;
    const int ar = 32*ti + (lane & 31);          // patch row
    const int ni = ar >> 3, nj = ar & 7;
    const float* pbase = xb + (ni*4 + 2*u2)*32 + nj*4;
    const int br = 32*tj + (lane & 31);          // q-dim
    const unsigned short* whp = WcH + ((size_t)(h*HD + br))*PFEAT;
    const unsigned short* wlp = WcL + ((size_t)(h*HD + br))*PFEAT;
    facc acc = {0,0,0,0,0,0,0,0,0,0,0,0,0,0,0,0};
    #pragma unroll
    for (int ks = 0; ks < 3; ++ks) {             // ks == color channel
      float4 va = *(const float4*)(pbase + ks*1024);
      float4 vb = *(const float4*)(pbase + ks*1024 + 32);
      B8 ah, al;
      ah.u[0] = cvt2(va.x, va.y); ah.u[1] = cvt2(va.z, va.w);
      ah.u[2] = cvt2(vb.x, vb.y); ah.u[3] = cvt2(vb.z, vb.w);
      al.u[0] = cvt2(va.x - lo16f(ah.u[0]), va.y - hi16f(ah.u[0]));
      al.u[1] = cvt2(va.z - lo16f(ah.u[1]), va.w - hi16f(ah.u[1]));
      al.u[2] = cvt2(vb.x - lo16f(ah.u[2]), vb.y - hi16f(ah.u[2]));
      al.u[3] = cvt2(vb.z - lo16f(ah.u[3]), vb.w - hi16f(ah.u[3]));
      const int f0 = ks*16 + u2*8;
      B8 bh, bl;
      bh.f = *(const bfrag*)(whp + f0);
      bl.f = *(const bfrag*)(wlp + f0);
      acc = __builtin_amdgcn_mfma_f32_32x32x16_bf16(ah.f, bh.f, acc, 0, 0, 0);
      acc = __builtin_amdgcn_mfma_f32_32x32x16_bf16(ah.f, bl.f, acc, 0, 0, 0);
      acc = __builtin_amdgcn_mfma_f32_32x32x16_bf16(al.f, bh.f, acc, 0, 0, 0);
    }
    #pragma unroll
    for (int r = 0; r < 16; ++r) {
      int row = (r & 3) + 8*(r >> 2) + 4*u2 + 32*ti;
      int s = 1 + row;
      Qh[s*68 + br] = f2bf(acc[r] + qb[s*HD + br]);
    }
    if (tid < HD) Qh[tid] = f2bf(qb[tid]);       // cls row s=0
    for (int i = tid; i < 31*17; i += 256) {     // zero rows 65..95
      int row = 65 + i/17, o = (i - (i/17)*17)*4;
      *(unsigned long long*)(Qh + row*68 + o) = 0ull;
    }
  }
  __syncthreads();   // A

  // ---- stage 2: S = Q·Q^T/8, 9 tiles of 32x32 over 96 padded rows ----
  for (int t = w; t < 9; t += 4) {
    const int ri = t/3, ci = t - ri*3;
    const int ar2 = 32*ri + (lane & 31);
    const int br2 = 32*ci + (lane & 31);
    facc a2 = {0,0,0,0,0,0,0,0,0,0,0,0,0,0,0,0};
    #pragma unroll
    for (int ks = 0; ks < 4; ++ks) {
      int k0 = ks*16 + u2*8;
      bfrag qa = ldf(Qh + ar2*68 + k0);
      bfrag qc = ldf(Qh + br2*68 + k0);
      a2 = __builtin_amdgcn_mfma_f32_32x32x16_bf16(qa, qc, a2, 0, 0, 0);
    }
    #pragma unroll
    for (int r = 0; r < 16; ++r) {
      int row = 32*ri + (r & 3) + 8*(r >> 2) + 4*u2;
      if (row < SEQL && br2 < SEQL) S[row*66 + br2] = a2[r]*0.125f;
    }
  }
  __syncthreads();   // B

  // ---- softmax over rows (== columns by symmetry), 4 partials per row ----
  {
    int r = tid >> 2, p = tid & 3;
    int c0 = p*17, c1 = (c0 + 17 < SEQL) ? c0 + 17 : SEQL;
    for (int row = r; row < SEQL; row += 64) {
      float m = -1e30f;
      for (int c = c0; c < c1; ++c) m = fmaxf(m, S[row*66 + c]);
      pmax_[row*4 + p] = m;
    }
  }
  __syncthreads();   // C1
  {
    int r = tid >> 2, p = tid & 3;
    int c0 = p*17, c1 = (c0 + 17 < SEQL) ? c0 + 17 : SEQL;
    for (int row = r; row < SEQL; row += 64) {
      float m = fmaxf(fmaxf(pmax_[row*4], pmax_[row*4+1]),
                      fmaxf(pmax_[row*4+2], pmax_[row*4+3]));
      float sum = 0.f;
      for (int c = c0; c < c1; ++c) sum += __expf(S[row*66 + c] - m);
      psum_[row*4 + p] = sum;
    }
  }
  __syncthreads();   // C2
  if (tid < SEQL) {
    float m = fmaxf(fmaxf(pmax_[tid*4], pmax_[tid*4+1]),
                    fmaxf(pmax_[tid*4+2], pmax_[tid*4+3]));
    float sum = psum_[tid*4] + psum_[tid*4+1] + psum_[tid*4+2] + psum_[tid*4+3];
    p0v[tid] = __expf(S[tid*66] - m) / sum;      // S[t][0] == S[0][t]
  }
  __syncthreads();   // D

  // ---- att0[k] = sum_t p0[t]*q[t][k] (4 partials; attp overlays pmax) ----
  {
    int k = tid & 63, p = tid >> 6;
    int t0 = p*17, t1 = (t0 + 17 < SEQL) ? t0 + 17 : SEQL;
    float a = 0.f;
    for (int t = t0; t < t1; ++t)
      a += p0v[t] * bf2f(Qh[t*68 + k]);
    attp[p*64 + k] = a;
  }
  __syncthreads();   // E
  if (tid < HD)
    mh0[(size_t)b*EMB + h*HD + tid] =
        attp[tid] + attp[64+tid] + attp[128+tid] + attp[192+tid];
}

// ---- K2/K3: split-K MFMA GEMM, atomic accumulate into memset-0 C.
//      C_partial[m][n] += A[m][kb..kb+256) @ W[n][kb..]^T ;  A optionally + abias[k].
template<bool ABIAS>
__global__ __launch_bounds__(256) void k_gemm(
    const float* __restrict__ A, const float* __restrict__ abias,
    const unsigned short* __restrict__ WH, const unsigned short* __restrict__ WL,
    float* __restrict__ C, int N, int K)
{
  __shared__ __align__(16) unsigned short Ah[64*36];
  __shared__ __align__(16) unsigned short Al[64*36];
  const int tid = threadIdx.x, w = tid >> 6, lane = tid & 63;
  const int u2 = lane >> 5;
  const int m0 = blockIdx.x*64, n0 = blockIdx.y*64, kb = blockIdx.z*256;
  const int ti = w >> 1, tj = w & 1;
  const int ar = 32*ti + (lane & 31);
  const int nr = n0 + 32*tj + (lane & 31);
  const unsigned short* wh = WH + (size_t)nr*K + kb;
  const unsigned short* wl = WL + (size_t)nr*K + kb;
  const int srow = tid >> 2, skk = (tid & 3)*8;
  const float* ap0 = A + (size_t)(m0 + srow)*K + kb + skk;
  facc acc = {0,0,0,0,0,0,0,0,0,0,0,0,0,0,0,0};

  for (int k0 = 0; k0 < 256; k0 += 32) {
    float4 a0 = *(const float4*)(ap0 + k0);
    float4 a1 = *(const float4*)(ap0 + k0 + 4);
    if (ABIAS) {
      float4 b0 = *(const float4*)(abias + kb + k0 + skk);
      float4 b1v = *(const float4*)(abias + kb + k0 + skk + 4);
      a0.x += b0.x; a0.y += b0.y; a0.z += b0.z; a0.w += b0.w;
      a1.x += b1v.x; a1.y += b1v.y; a1.z += b1v.z; a1.w += b1v.w;
    }
    B8 sh, sl;
    sh.u[0] = cvt2(a0.x, a0.y); sh.u[1] = cvt2(a0.z, a0.w);
    sh.u[2] = cvt2(a1.x, a1.y); sh.u[3] = cvt2(a1.z, a1.w);
    sl.u[0] = cvt2(a0.x - lo16f(sh.u[0]), a0.y - hi16f(sh.u[0]));
    sl.u[1] = cvt2(a0.z - lo16f(sh.u[1]), a0.w - hi16f(sh.u[1]));
    sl.u[2] = cvt2(a1.x - lo16f(sh.u[2]), a1.y - hi16f(sh.u[2]));
    sl.u[3] = cvt2(a1.z - lo16f(sh.u[3]), a1.w - hi16f(sh.u[3]));
    *(unsigned long long*)(Ah + srow*36 + skk)     = sh.ull[0];
    *(unsigned long long*)(Ah + srow*36 + skk + 4) = sh.ull[1];
    *(unsigned long long*)(Al + srow*36 + skk)     = sl.ull[0];
    *(unsigned long long*)(Al + srow*36 + skk + 4) = sl.ull[1];
    __syncthreads();
    #pragma unroll
    for (int ks = 0; ks < 2; ++ks) {
      int f0 = ks*16 + u2*8;
      bfrag ah = ldf(Ah + ar*36 + f0);
      bfrag al = ldf(Al + ar*36 + f0);
      B8 bh, bl;
      bh.f = *(const bfrag*)(wh + k0 + f0);
      bl.f = *(const bfrag*)(wl + k0 + f0);
      acc = __builtin_amdgcn_mfma_f32_32x32x16_bf16(ah, bh.f, acc, 0, 0, 0);
      acc = __builtin_amdgcn_mfma_f32_32x32x16_bf16(ah, bl.f, acc, 0, 0, 0);
      acc = __builtin_amdgcn_mfma_f32_32x32x16_bf16(al, bh.f, acc, 0, 0, 0);
    }
    __syncthreads();
  }
  #pragma unroll
  for (int r = 0; r < 16; ++r) {
    int m = m0 + 32*ti + (r & 3) + 8*(r >> 2) + 4*u2;
    atomicAdd(&C[(size_t)m*N + nr], acc[r]);
  }
}

// ---- K4: logits = gelu(hh + b1) @ w2^T + b2 ; one wave per batch row ----
__global__ __launch_bounds__(256) void k_logits(
    const float* __restrict__ hh, const float* __restrict__ b1,
    const float* __restrict__ w2, const float* __restrict__ b2,
    float* __restrict__ out)
{
  const int w = threadIdx.x >> 6, lane = threadIdx.x & 63;
  const int r = blockIdx.x*4 + w;
  const float* hr = hh + (size_t)r*HIDDIM + lane*16;
  const float* br = b1 + lane*16;
  float hv[16];
  #pragma unroll
  for (int i4 = 0; i4 < 4; ++i4) {
    float4 v  = *(const float4*)(hr + i4*4);
    float4 bb = *(const float4*)(br + i4*4);
    float c0 = v.x + bb.x, c1 = v.y + bb.y, c2 = v.z + bb.z, c3 = v.w + bb.w;
    hv[i4*4+0] = 0.5f*c0*(1.f + erff(c0*0.70710678118654752f));
    hv[i4*4+1] = 0.5f*c1*(1.f + erff(c1*0.70710678118654752f));
    hv[i4*4+2] = 0.5f*c2*(1.f + erff(c2*0.70710678118654752f));
    hv[i4*4+3] = 0.5f*c3*(1.f + erff(c3*0.70710678118654752f));
  }
  float acc[NCLS];
  #pragma unroll
  for (int c = 0; c < NCLS; ++c) {
    const float* wr = w2 + (size_t)c*HIDDIM + lane*16;
    float a = 0.f;
    #pragma unroll
    for (int i4 = 0; i4 < 4; ++i4) {
      float4 wv = *(const float4*)(wr + i4*4);
      a += hv[i4*4]*wv.x + hv[i4*4+1]*wv.y + hv[i4*4+2]*wv.z + hv[i4*4+3]*wv.w;
    }
    acc[c] = a;
  }
  #pragma unroll
  for (int c = 0; c < NCLS; ++c)
    #pragma unroll
    for (int m = 1; m < 64; m <<= 1) acc[c] += __shfl_xor(acc[c], m, 64);
  if (lane == 0) {
    #pragma unroll
    for (int c = 0; c < NCLS; ++c) out[(size_t)r*NCLS + c] = acc[c] + b2[c];
  }
}

extern "C" void kernel_launch(void* const* d_in, const int* in_sizes, int n_in,
                              void* d_out, int out_size, void* d_ws, size_t ws_size,
                              hipStream_t stream)
{
  const float* x      = (const float*)d_in[0];
  const float* proj_w = (const float*)d_in[1];
  const float* proj_b = (const float*)d_in[2];
  const float* cls    = (const float*)d_in[3];
  const float* pos    = (const float*)d_in[4];
  const float* wq     = (const float*)d_in[5];
  const float* bq     = (const float*)d_in[6];
  const float* wo     = (const float*)d_in[7];
  const float* bo     = (const float*)d_in[8];
  const float* w1     = (const float*)d_in[9];
  const float* b1     = (const float*)d_in[10];
  const float* w2     = (const float*)d_in[11];
  const float* b2     = (const float*)d_in[12];
  float* out = (float*)d_out;

  // ws layout (bytes), total 20,154,368 (same footprint as round 5):
  unsigned short* WcH = (unsigned short*)d_ws;                         // 49152
  unsigned short* WcL = (unsigned short*)((char*)d_ws + 49152);        // 49152
  float* qbias        = (float*)((char*)d_ws + 98304);                 // 133120
  unsigned short* WoH = (unsigned short*)((char*)d_ws + 231424);       // 524288
  unsigned short* WoL = (unsigned short*)((char*)d_ws + 755712);       // 524288
  unsigned short* W1H = (unsigned short*)((char*)d_ws + 1280000);      // 1048576
  unsigned short* W1L = (unsigned short*)((char*)d_ws + 2328576);      // 1048576
  float* mh0          = (float*)((char*)d_ws + 3377152);               // 4 MB
  float* ct           = (float*)((char*)d_ws + 7571456);               // 4 MB
  float* hh           = (float*)((char*)d_ws + 11765760);              // 8 MB

  hipMemsetAsync(ct, 0, (size_t)BATCH*EMB*4, stream);
  hipMemsetAsync(hh, 0, (size_t)BATCH*HIDDIM*4, stream);

  hipLaunchKernelGGL(k_pack,  dim3(EMB), dim3(256), 0, stream, wq, proj_w, WcH, WcL);
  hipLaunchKernelGGL(k_qbias, dim3(NHEADS*SEQL), dim3(256), 0, stream, wq, bq, cls, pos, proj_b, qbias);
  hipLaunchKernelGGL(k_packw, dim3(1024), dim3(256), 0, stream, wo, WoH, WoL, EMB*EMB);
  hipLaunchKernelGGL(k_packw, dim3(2048), dim3(256), 0, stream, w1, W1H, W1L, HIDDIM*EMB);

  hipLaunchKernelGGL(k_attn, dim3(BATCH*NHEADS), dim3(256), 0, stream,
                     x, WcH, WcL, qbias, mh0);

  hipLaunchKernelGGL((k_gemm<false>), dim3(BATCH/64, EMB/64, 2), dim3(256), 0, stream,
                     mh0, (const float*)nullptr, WoH, WoL, ct, EMB, EMB);
  hipLaunchKernelGGL((k_gemm<true>),  dim3(BATCH/64, HIDDIM/64, 2), dim3(256), 0, stream,
                     ct, bo, W1H, W1L, hh, HIDDIM, EMB);
  hipLaunchKernelGGL(k_logits, dim3(BATCH/4), dim3(256), 0, stream,
                     hh, b1, w2, b2, out);
}

// Round 7
// 250.720 us; speedup vs baseline: 2.9939x; 1.2825x over previous
//
#include <hip/hip_runtime.h>
#include <hip/hip_bf16.h>
#include <math.h>

#define BATCH 2048
#define SEQL 65
#define EMB 512
#define NHEADS 8
#define HD 64
#define NPATCH 64
#define PFEAT 48
#define HIDDIM 1024
#define NCLS 10

typedef short bfrag __attribute__((ext_vector_type(8)));   // 8 bf16 (4 VGPRs)
typedef float facc  __attribute__((ext_vector_type(16)));  // 16 f32 acc

union B8 { unsigned int u[4]; unsigned long long ull[2]; bfrag f; };

__device__ inline unsigned int cvt2(float a, float b) {     // 2x f32 -> packed bf16 (RTNE)
  __hip_bfloat162 t = __float22bfloat162_rn(float2{a, b});
  return *(unsigned int*)&t;
}
__device__ inline unsigned short f2bf(float f) {
  __hip_bfloat16 h = __float2bfloat16(f);
  return *(unsigned short*)&h;
}
__device__ inline float bf2f(unsigned short h) {
  return __uint_as_float(((unsigned int)h) << 16);
}
__device__ inline float lo16f(unsigned int u) { return __uint_as_float(u << 16); }
__device__ inline float hi16f(unsigned int u) { return __uint_as_float(u & 0xffff0000u); }
__device__ inline bfrag ldf(const unsigned short* p) {      // LDS: 2x ds_read_b64
  union { unsigned long long u[2]; bfrag s; } c;
  c.u[0] = *(const unsigned long long*)(p);
  c.u[1] = *(const unsigned long long*)(p + 4);
  return c.s;
}

// ---- K0: fused preprocessing.
// blocks [0,512): Wc = wq@proj_w -> bf16 hi/lo ; [512,1536): pack wo ; [1536,3584): pack w1 ;
// [3584,3840): transpose wq -> wqT[d][hk]
__global__ __launch_bounds__(256) void k_prep(
    const float* __restrict__ wq, const float* __restrict__ proj_w,
    unsigned short* __restrict__ WcH, unsigned short* __restrict__ WcL,
    const float* __restrict__ wo, unsigned short* __restrict__ WoH,
    unsigned short* __restrict__ WoL,
    const float* __restrict__ w1, unsigned short* __restrict__ W1H,
    unsigned short* __restrict__ W1L,
    float* __restrict__ wqT)
{
  __shared__ float sm[1088];
  const int bid = blockIdx.x, tid = threadIdx.x;
  if (bid < 512) {                       // ---- Wc pack (hk = bid) ----
    float* wr = sm;                      // 512
    float* part = sm + 512;              // 192
    const int hk = bid;
    wr[tid]     = wq[(size_t)hk*EMB + tid];
    wr[256+tid] = wq[(size_t)hk*EMB + 256 + tid];
    __syncthreads();
    if (tid < PFEAT*4) {
      int f = tid % PFEAT, p = tid / PFEAT;
      float a = 0.f;
      for (int d = p*128; d < (p+1)*128; ++d) a += wr[d]*proj_w[d*PFEAT + f];
      part[p*PFEAT + f] = a;
    }
    __syncthreads();
    if (tid < PFEAT) {
      float v = part[tid] + part[PFEAT+tid] + part[2*PFEAT+tid] + part[3*PFEAT+tid];
      unsigned short hi = f2bf(v);
      WcH[hk*PFEAT + tid] = hi;
      WcL[hk*PFEAT + tid] = f2bf(v - bf2f(hi));
    }
  } else if (bid < 1536) {               // ---- pack wo ----
    int i = (bid - 512)*256 + tid;
    float v = wo[i];
    unsigned short hi = f2bf(v);
    WoH[i] = hi; WoL[i] = f2bf(v - bf2f(hi));
  } else if (bid < 3584) {               // ---- pack w1 ----
    int i = (bid - 1536)*256 + tid;
    float v = w1[i];
    unsigned short hi = f2bf(v);
    W1H[i] = hi; W1L[i] = f2bf(v - bf2f(hi));
  } else {                               // ---- transpose wq (32x32 tiles) ----
    float (*t)[33] = (float(*)[33])sm;
    const int r = bid - 3584, bx = (r & 15)*32, by = (r >> 4)*32;
    const int c = tid & 31, r0 = tid >> 5;
    #pragma unroll
    for (int i = 0; i < 4; ++i) {
      int rr = r0 + 8*i;
      t[rr][c] = wq[(size_t)(by + rr)*512 + bx + c];
    }
    __syncthreads();
    #pragma unroll
    for (int i = 0; i < 4; ++i) {
      int rr = r0 + 8*i;
      wqT[(size_t)(bx + rr)*512 + by + c] = t[c][rr];
    }
  }
}

// ---- K0b: qbias[h][s][k] = (pos[s] + (s? proj_b : cls)) . wqT[:, h*64+k] + bq[h,k] ----
__global__ __launch_bounds__(256) void k_qbias(
    const float* __restrict__ wqT, const float* __restrict__ bq,
    const float* __restrict__ cls, const float* __restrict__ pos,
    const float* __restrict__ proj_b, float* __restrict__ qbias)
{
  __shared__ float v[EMB];
  __shared__ float part[256];
  const int h = blockIdx.x / SEQL, s = blockIdx.x - h*SEQL;
  const int tid = threadIdx.x;
  const float* po = pos + (size_t)s*EMB;
  v[tid]     = po[tid]     + (s == 0 ? cls[tid]     : proj_b[tid]);
  v[256+tid] = po[256+tid] + (s == 0 ? cls[256+tid] : proj_b[256+tid]);
  __syncthreads();
  const int p = tid >> 6, k = tid & 63;
  const float* wp = wqT + h*HD + k;
  float a = 0.f;
  for (int d = p*128; d < p*128 + 128; ++d)
    a = fmaf(v[d], wp[(size_t)d*512], a);
  part[p*64 + k] = a;
  __syncthreads();
  if (tid < HD)
    qbias[((size_t)h*SEQL + s)*HD + tid] =
        part[tid] + part[64+tid] + part[128+tid] + part[192+tid] + bq[h*HD + tid];
}

// ---- K1: block per (b,h), id = h*2048+b. Direct-from-global A-frags; Q bf16 in LDS;
// S never materialized: per-tile in-register flash-softmax partials (m,s) + row-0 strip.
// LDS: Qh[96*68]u16 13056 | mpart[6*96] | spart[6*96] | S0[96] | p0[96] | attp[256] = 19456 B
__global__ __launch_bounds__(256) void k_attn(
    const float* __restrict__ x, const unsigned short* __restrict__ WcH,
    const unsigned short* __restrict__ WcL, const float* __restrict__ qbias,
    float* __restrict__ mh0)
{
  __shared__ __align__(16) char smem[19456];
  unsigned short* Qh = (unsigned short*)smem;           // 96*68 u16
  float* mpart = (float*)(smem + 13056);                // 6*96
  float* spart = (float*)(smem + 15360);                // 6*96
  float* S0    = (float*)(smem + 17664);                // 96
  float* p0v   = (float*)(smem + 18048);                // 96
  float* attp  = (float*)(smem + 18432);                // 256

  const int b = blockIdx.x & 2047, h = blockIdx.x >> 11;
  const int tid = threadIdx.x, w = tid >> 6, lane = tid & 63;
  const int u2 = lane >> 5;            // k-fragment half (0/1)
  const float* xb = x + (size_t)b*3072;
  const float* qb = qbias + (size_t)h*SEQL*HD;
  const float C = 0.18033688011112042f;   // log2(e)/8

  // ---- stage 1: q = P·Wc_h^T + qbias; A from global, B from global/L2 ----
  {
    const int ti = w >> 1, tj = w & 1;
    const int ar = 32*ti + (lane & 31);          // patch row
    const int ni = ar >> 3, nj = ar & 7;
    const float* pbase = xb + (ni*4 + 2*u2)*32 + nj*4;
    const int br = 32*tj + (lane & 31);          // q-dim
    const unsigned short* whp = WcH + ((size_t)(h*HD + br))*PFEAT;
    const unsigned short* wlp = WcL + ((size_t)(h*HD + br))*PFEAT;
    facc acc = {0,0,0,0,0,0,0,0,0,0,0,0,0,0,0,0};
    #pragma unroll
    for (int ks = 0; ks < 3; ++ks) {             // ks == color channel
      float4 va = *(const float4*)(pbase + ks*1024);
      float4 vb = *(const float4*)(pbase + ks*1024 + 32);
      B8 ah, al;
      ah.u[0] = cvt2(va.x, va.y); ah.u[1] = cvt2(va.z, va.w);
      ah.u[2] = cvt2(vb.x, vb.y); ah.u[3] = cvt2(vb.z, vb.w);
      al.u[0] = cvt2(va.x - lo16f(ah.u[0]), va.y - hi16f(ah.u[0]));
      al.u[1] = cvt2(va.z - lo16f(ah.u[1]), va.w - hi16f(ah.u[1]));
      al.u[2] = cvt2(vb.x - lo16f(ah.u[2]), vb.y - hi16f(ah.u[2]));
      al.u[3] = cvt2(vb.z - lo16f(ah.u[3]), vb.w - hi16f(ah.u[3]));
      const int f0 = ks*16 + u2*8;
      B8 bh, bl;
      bh.f = *(const bfrag*)(whp + f0);
      bl.f = *(const bfrag*)(wlp + f0);
      acc = __builtin_amdgcn_mfma_f32_32x32x16_bf16(ah.f, bh.f, acc, 0, 0, 0);
      acc = __builtin_amdgcn_mfma_f32_32x32x16_bf16(ah.f, bl.f, acc, 0, 0, 0);
      acc = __builtin_amdgcn_mfma_f32_32x32x16_bf16(al.f, bh.f, acc, 0, 0, 0);
    }
    #pragma unroll
    for (int r = 0; r < 16; ++r) {
      int row = (r & 3) + 8*(r >> 2) + 4*u2 + 32*ti;
      int s = 1 + row;
      Qh[s*68 + br] = f2bf(acc[r] + qb[s*HD + br]);
    }
    if (tid < HD) Qh[tid] = f2bf(qb[tid]);       // cls row s=0
    for (int i = tid; i < 31*17; i += 256) {     // zero rows 65..95
      int row = 65 + i/17, o = (i - (i/17)*17)*4;
      *(unsigned long long*)(Qh + row*68 + o) = 0ull;
    }
  }
  __syncthreads();   // A: Q complete

  // ---- stage 2: per-tile MFMA + in-register column stats (flash partials) ----
  for (int t = w; t < 9; t += 4) {
    const int ri = t/3, ci = t - ri*3;
    const int ar2 = 32*ri + (lane & 31);
    const int br2 = 32*ci + (lane & 31);     // this lane's column
    facc a2 = {0,0,0,0,0,0,0,0,0,0,0,0,0,0,0,0};
    #pragma unroll
    for (int ks = 0; ks < 4; ++ks) {
      int k0 = ks*16 + u2*8;
      bfrag qa = ldf(Qh + ar2*68 + k0);
      bfrag qc = ldf(Qh + br2*68 + k0);
      a2 = __builtin_amdgcn_mfma_f32_32x32x16_bf16(qa, qc, a2, 0, 0, 0);
    }
    float m, s;
    if (ri == 2) {                // only row 64 valid (reg 0, lanes<32)
      m = (u2 == 0) ? a2[0] : -3.0e38f;
      s = (u2 == 0) ? 1.0f : 0.0f;
    } else {
      m = a2[0];
      #pragma unroll
      for (int r = 1; r < 16; ++r) m = fmaxf(m, a2[r]);
      float mm = m * C;
      s = 0.f;
      #pragma unroll
      for (int r = 0; r < 16; ++r)
        s += __builtin_amdgcn_exp2f(fmaf(a2[r], C, -mm));
    }
    const int pi = ri*2 + u2;
    mpart[pi*96 + br2] = m;
    spart[pi*96 + br2] = s;
    if (ri == 0 && u2 == 0) S0[br2] = a2[0];   // S[0][col] (raw)
  }
  __syncthreads();   // B

  // ---- merge partials -> p0 (only columns < 65 used) ----
  if (tid < SEQL) {
    float m = mpart[tid];
    #pragma unroll
    for (int i = 1; i < 6; ++i) m = fmaxf(m, mpart[i*96 + tid]);
    float mm = m * C;
    float s = 0.f;
    #pragma unroll
    for (int i = 0; i < 6; ++i)
      s += spart[i*96 + tid] * __builtin_amdgcn_exp2f(fmaf(mpart[i*96 + tid], C, -mm));
    p0v[tid] = __builtin_amdgcn_exp2f(fmaf(S0[tid], C, -mm)) / s;
  }
  __syncthreads();   // C

  // ---- att0[k] = sum_t p0[t]*q[t][k] (4 partials) ----
  {
    int k = tid & 63, p = tid >> 6;
    int t0 = p*17, t1 = (t0 + 17 < SEQL) ? t0 + 17 : SEQL;
    float a = 0.f;
    for (int t = t0; t < t1; ++t)
      a += p0v[t] * bf2f(Qh[t*68 + k]);
    attp[p*64 + k] = a;
  }
  __syncthreads();   // D
  if (tid < HD)
    mh0[(size_t)b*EMB + h*HD + tid] =
        attp[tid] + attp[64+tid] + attp[128+tid] + attp[192+tid];
}

// ---- K2/K3: MFMA split-bf16 GEMM, direct write: C = A @ W^T + bias (opt. exact GELU) ----
template<bool GELU>
__global__ __launch_bounds__(256) void k_gemm(
    const float* __restrict__ A, const unsigned short* __restrict__ WH,
    const unsigned short* __restrict__ WL, const float* __restrict__ bias,
    float* __restrict__ C, int N, int K)
{
  __shared__ __align__(16) unsigned short Ah[64*36];
  __shared__ __align__(16) unsigned short Al[64*36];
  const int tid = threadIdx.x, w = tid >> 6, lane = tid & 63;
  const int u2 = lane >> 5;
  const int m0 = blockIdx.x*64, n0 = blockIdx.y*64;
  const int ti = w >> 1, tj = w & 1;
  const int ar = 32*ti + (lane & 31);
  const int nr = n0 + 32*tj + (lane & 31);
  const unsigned short* wh = WH + (size_t)nr*K;
  const unsigned short* wl = WL + (size_t)nr*K;
  const int srow = tid >> 2, skk = (tid & 3)*8;
  const float* ap0 = A + (size_t)(m0 + srow)*K + skk;
  facc acc = {0,0,0,0,0,0,0,0,0,0,0,0,0,0,0,0};

  for (int k0 = 0; k0 < K; k0 += 32) {
    float4 a0 = *(const float4*)(ap0 + k0);
    float4 a1 = *(const float4*)(ap0 + k0 + 4);
    B8 sh, sl;
    sh.u[0] = cvt2(a0.x, a0.y); sh.u[1] = cvt2(a0.z, a0.w);
    sh.u[2] = cvt2(a1.x, a1.y); sh.u[3] = cvt2(a1.z, a1.w);
    sl.u[0] = cvt2(a0.x - lo16f(sh.u[0]), a0.y - hi16f(sh.u[0]));
    sl.u[1] = cvt2(a0.z - lo16f(sh.u[1]), a0.w - hi16f(sh.u[1]));
    sl.u[2] = cvt2(a1.x - lo16f(sh.u[2]), a1.y - hi16f(sh.u[2]));
    sl.u[3] = cvt2(a1.z - lo16f(sh.u[3]), a1.w - hi16f(sh.u[3]));
    *(unsigned long long*)(Ah + srow*36 + skk)     = sh.ull[0];
    *(unsigned long long*)(Ah + srow*36 + skk + 4) = sh.ull[1];
    *(unsigned long long*)(Al + srow*36 + skk)     = sl.ull[0];
    *(unsigned long long*)(Al + srow*36 + skk + 4) = sl.ull[1];
    __syncthreads();
    #pragma unroll
    for (int ks = 0; ks < 2; ++ks) {
      int f0 = ks*16 + u2*8;
      bfrag ah = ldf(Ah + ar*36 + f0);
      bfrag al = ldf(Al + ar*36 + f0);
      B8 bh, bl;
      bh.f = *(const bfrag*)(wh + k0 + f0);
      bl.f = *(const bfrag*)(wl + k0 + f0);
      acc = __builtin_amdgcn_mfma_f32_32x32x16_bf16(ah, bh.f, acc, 0, 0, 0);
      acc = __builtin_amdgcn_mfma_f32_32x32x16_bf16(ah, bl.f, acc, 0, 0, 0);
      acc = __builtin_amdgcn_mfma_f32_32x32x16_bf16(al, bh.f, acc, 0, 0, 0);
    }
    __syncthreads();
  }
  #pragma unroll
  for (int r = 0; r < 16; ++r) {
    int m = m0 + 32*ti + (r & 3) + 8*(r >> 2) + 4*u2;
    float c = acc[r] + bias[nr];
    if (GELU) c = 0.5f*c*(1.f + erff(c*0.70710678118654752f));
    C[(size_t)m*N + nr] = c;
  }
}

// ---- K4: logits = hh @ w2^T + b2 ; one wave per batch row ----
__global__ __launch_bounds__(256) void k_logits(
    const float* __restrict__ hh, const float* __restrict__ w2,
    const float* __restrict__ b2, float* __restrict__ out)
{
  const int w = threadIdx.x >> 6, lane = threadIdx.x & 63;
  const int r = blockIdx.x*4 + w;
  const float* hr = hh + (size_t)r*HIDDIM + lane*16;
  float hv[16];
  #pragma unroll
  for (int i4 = 0; i4 < 4; ++i4) {
    float4 v = *(const float4*)(hr + i4*4);
    hv[i4*4+0] = v.x; hv[i4*4+1] = v.y; hv[i4*4+2] = v.z; hv[i4*4+3] = v.w;
  }
  float acc[NCLS];
  #pragma unroll
  for (int c = 0; c < NCLS; ++c) {
    const float* wr = w2 + (size_t)c*HIDDIM + lane*16;
    float a = 0.f;
    #pragma unroll
    for (int i4 = 0; i4 < 4; ++i4) {
      float4 wv = *(const float4*)(wr + i4*4);
      a += hv[i4*4]*wv.x + hv[i4*4+1]*wv.y + hv[i4*4+2]*wv.z + hv[i4*4+3]*wv.w;
    }
    acc[c] = a;
  }
  #pragma unroll
  for (int c = 0; c < NCLS; ++c)
    #pragma unroll
    for (int m = 1; m < 64; m <<= 1) acc[c] += __shfl_xor(acc[c], m, 64);
  if (lane == 0) {
    #pragma unroll
    for (int c = 0; c < NCLS; ++c) out[(size_t)r*NCLS + c] = acc[c] + b2[c];
  }
}

extern "C" void kernel_launch(void* const* d_in, const int* in_sizes, int n_in,
                              void* d_out, int out_size, void* d_ws, size_t ws_size,
                              hipStream_t stream)
{
  const float* x      = (const float*)d_in[0];
  const float* proj_w = (const float*)d_in[1];
  const float* proj_b = (const float*)d_in[2];
  const float* cls    = (const float*)d_in[3];
  const float* pos    = (const float*)d_in[4];
  const float* wq     = (const float*)d_in[5];
  const float* bq     = (const float*)d_in[6];
  const float* wo     = (const float*)d_in[7];
  const float* bo     = (const float*)d_in[8];
  const float* w1     = (const float*)d_in[9];
  const float* b1     = (const float*)d_in[10];
  const float* w2     = (const float*)d_in[11];
  const float* b2     = (const float*)d_in[12];
  float* out = (float*)d_out;

  // ws layout (bytes), total 20,154,368 (same as round 6).
  // wqT overlays hh: written by k_prep, read by k_qbias, later overwritten by gemm<true>.
  unsigned short* WcH = (unsigned short*)d_ws;                         // 49152
  unsigned short* WcL = (unsigned short*)((char*)d_ws + 49152);        // 49152
  float* qbias        = (float*)((char*)d_ws + 98304);                 // 133120
  unsigned short* WoH = (unsigned short*)((char*)d_ws + 231424);       // 524288
  unsigned short* WoL = (unsigned short*)((char*)d_ws + 755712);       // 524288
  unsigned short* W1H = (unsigned short*)((char*)d_ws + 1280000);      // 1048576
  unsigned short* W1L = (unsigned short*)((char*)d_ws + 2328576);      // 1048576
  float* mh0          = (float*)((char*)d_ws + 3377152);               // 4 MB
  float* ct           = (float*)((char*)d_ws + 7571456);               // 4 MB
  float* hh           = (float*)((char*)d_ws + 11765760);              // 8 MB
  float* wqT          = hh;                                            // 1 MB overlay

  hipLaunchKernelGGL(k_prep, dim3(3840), dim3(256), 0, stream,
                     wq, proj_w, WcH, WcL, wo, WoH, WoL, w1, W1H, W1L, wqT);
  hipLaunchKernelGGL(k_qbias, dim3(NHEADS*SEQL), dim3(256), 0, stream,
                     wqT, bq, cls, pos, proj_b, qbias);
  hipLaunchKernelGGL(k_attn, dim3(BATCH*NHEADS), dim3(256), 0, stream,
                     x, WcH, WcL, qbias, mh0);
  hipLaunchKernelGGL((k_gemm<false>), dim3(BATCH/64, EMB/64), dim3(256), 0, stream,
                     mh0, WoH, WoL, bo, ct, EMB, EMB);
  hipLaunchKernelGGL((k_gemm<true>),  dim3(BATCH/64, HIDDIM/64), dim3(256), 0, stream,
                     ct, W1H, W1L, b1, hh, HIDDIM, EMB);
  hipLaunchKernelGGL(k_logits, dim3(BATCH/4), dim3(256), 0, stream,
                     hh, w2, b2, out);
}